// Round 7
// baseline (685.610 us; speedup 1.0000x reference)
//
#include <hip/hip_runtime.h>
#include <math.h>

// Shapes (fixed)
#define BB 8
#define SEQ 2049
#define NT 2048
#define DD 1024
#define EE 8
#define SS 256
#define ESN 2048
#define HH 512

typedef __bf16 bf16x8 __attribute__((ext_vector_type(8)));
typedef float f32x4 __attribute__((ext_vector_type(4)));

__device__ __forceinline__ float gelu_f(float v) {
  return 0.5f * v * (1.0f + erff(v * 0.70710678118654752440f));
}
__device__ __forceinline__ float wave_sum(float v) {
#pragma unroll
  for (int off = 1; off < 64; off <<= 1) v += __shfl_xor(v, off);
  return v;
}
__device__ __forceinline__ unsigned short f2bf(float f) {
  unsigned int u = __float_as_uint(f);
  u = (u + 0x7fffu + ((u >> 16) & 1u)) >> 16;
  return (unsigned short)u;
}
__device__ __forceinline__ float bf2f(unsigned short h) {
  return __uint_as_float(((unsigned int)h) << 16);
}

// async 16B/lane global->LDS stage; lbase is wave-uniform, HW adds lane*16.
__device__ __forceinline__ void stage16(const unsigned short* g, unsigned short* lbase, int lane) {
#if __has_builtin(__builtin_amdgcn_global_load_lds)
  __builtin_amdgcn_global_load_lds((const __attribute__((address_space(1))) void*)g,
                                   (__attribute__((address_space(3))) void*)lbase, 16, 0, 0);
#else
  *(int4*)(lbase + lane * 8) = *(const int4*)g;
#endif
}

// ---- bf16 gemm_bt core: C[128x128]=A[m][k]*B[n][k]^T, K%64==0 ----
// Round-2 sync structure (stage -> barrier -> compute -> barrier), BK=64:
// one barrier pair per 64 K. LDS: A 2x[128][32] at kk*4096, B at +8192.
__device__ __forceinline__ void gemm_core(const unsigned short* __restrict__ A,
                                          const unsigned short* __restrict__ B,
                                          int K, unsigned short* LDS, f32x4 acc[4][4]) {
  const int t = threadIdx.x;
  const int lane = t & 63, wave = t >> 6;
  const int srow = t >> 2, scol = (t & 3) * 8;   // srow 0..63
  const int fr = lane & 15, fk = (lane >> 4) * 8;
  const int wm = (wave >> 1) * 64, wn = (wave & 1) * 64;
  const unsigned short* a0 = A + (size_t)srow * K + scol;
  const unsigned short* a1 = A + (size_t)(srow + 64) * K + scol;
  const unsigned short* b0 = B + (size_t)srow * K + scol;
  const unsigned short* b1 = B + (size_t)(srow + 64) * K + scol;
  unsigned short* dA = LDS + wave * 512;
  unsigned short* dB = LDS + 8192 + wave * 512;
  for (int k0 = 0; k0 < K; k0 += 64) {
#pragma unroll
    for (int kk = 0; kk < 2; ++kk) {
      stage16(a0 + k0 + kk * 32, dA + kk * 4096, lane);
      stage16(a1 + k0 + kk * 32, dA + kk * 4096 + 2048, lane);
      stage16(b0 + k0 + kk * 32, dB + kk * 4096, lane);
      stage16(b1 + k0 + kk * 32, dB + kk * 4096 + 2048, lane);
    }
    __syncthreads();  // drains vmcnt: staged tiles visible
#pragma unroll
    for (int kk = 0; kk < 2; ++kk) {
      bf16x8 af[4], bfr[4];
#pragma unroll
      for (int i = 0; i < 4; ++i)
        af[i] = *(const bf16x8*)(LDS + kk * 4096 + (wm + i * 16 + fr) * 32 + fk);
#pragma unroll
      for (int j = 0; j < 4; ++j)
        bfr[j] = *(const bf16x8*)(LDS + 8192 + kk * 4096 + (wn + j * 16 + fr) * 32 + fk);
#pragma unroll
      for (int i = 0; i < 4; ++i)
#pragma unroll
        for (int j = 0; j < 4; ++j)
          acc[i][j] = __builtin_amdgcn_mfma_f32_16x16x32_bf16(af[i], bfr[j], acc[i][j], 0, 0, 0);
    }
    __syncthreads();  // all reads done before next stage overwrites
  }
}

#define ACC_INIT()                                        \
  f32x4 acc[4][4];                                        \
  _Pragma("unroll") for (int i = 0; i < 4; ++i)           \
  _Pragma("unroll") for (int j = 0; j < 4; ++j)           \
  _Pragma("unroll") for (int r = 0; r < 4; ++r) acc[i][j][r] = 0.f;

#define GEMM_EPI_VARS()                                   \
  const int lane = threadIdx.x & 63, wave = threadIdx.x >> 6; \
  const int wm = (wave >> 1) * 64, wn = (wave & 1) * 64;  \
  const int fr16 = lane & 15, r4 = (lane >> 4) << 2;

// logits -> E16[n][c] direct + row/col stat partials + ET[c][n] via LDS transpose.
__global__ __launch_bounds__(256) void k_logits_mfma(const unsigned short* __restrict__ Xb,
    const unsigned short* __restrict__ MT, unsigned short* __restrict__ E16,
    unsigned short* __restrict__ ET, float* __restrict__ pr1, float* __restrict__ pr2,
    float* __restrict__ pc1, float* __restrict__ pc2) {
  __shared__ unsigned short LDS[16384];
  ACC_INIT();
  const int b = blockIdx.z, m0 = blockIdx.x * 128, n0 = blockIdx.y * 128;
  gemm_core(Xb + ((size_t)b * NT + m0) * DD, MT + (size_t)n0 * DD, DD, LDS, acc);
  GEMM_EPI_VARS();
  const int t = threadIdx.x;
  unsigned short* o = E16 + (size_t)b * NT * ESN;
  const int cblk = (n0 >> 6) + (wn >> 6);
  const int rblk = (m0 >> 6) + (wm >> 6);
  float cs1[4] = {0.f, 0.f, 0.f, 0.f}, cs2[4] = {0.f, 0.f, 0.f, 0.f};
#pragma unroll
  for (int i = 0; i < 4; ++i) {
    const int gmb = m0 + wm + i * 16 + r4;
    float rs1[4] = {0.f, 0.f, 0.f, 0.f}, rs2[4] = {0.f, 0.f, 0.f, 0.f};
#pragma unroll
    for (int j = 0; j < 4; ++j) {
      const int gn = n0 + wn + j * 16 + fr16;
#pragma unroll
      for (int r = 0; r < 4; ++r) {
        const float ev = expf(acc[i][j][r]);
        o[(size_t)(gmb + r) * ESN + gn] = f2bf(ev);
        rs1[r] += ev; rs2[r] = fmaf(ev, ev, rs2[r]);
        cs1[j] += ev; cs2[j] = fmaf(ev, ev, cs2[j]);
      }
    }
#pragma unroll
    for (int r = 0; r < 4; ++r) {
#pragma unroll
      for (int m = 1; m < 16; m <<= 1) {
        rs1[r] += __shfl_xor(rs1[r], m);
        rs2[r] += __shfl_xor(rs2[r], m);
      }
    }
    if (fr16 == 0) {
#pragma unroll
      for (int r = 0; r < 4; ++r) {
        pr1[((size_t)b * NT + gmb + r) * 32 + cblk] = rs1[r];
        pr2[((size_t)b * NT + gmb + r) * 32 + cblk] = rs2[r];
      }
    }
  }
  // RACE FIX (round 6 bug): cs1/cs2 are per-row-quad partials; the 4 lanes
  // sharing fr16 (lane bits 4-5) hold disjoint 16-row pieces of the wave's
  // 64-row block and wrote the SAME pc address. Reduce across lane^16/^32
  // first, then write once from lanes 0-15.
#pragma unroll
  for (int j = 0; j < 4; ++j) {
    cs1[j] += __shfl_xor(cs1[j], 16);
    cs2[j] += __shfl_xor(cs2[j], 16);
    cs1[j] += __shfl_xor(cs1[j], 32);
    cs2[j] += __shfl_xor(cs2[j], 32);
  }
  if (lane < 16) {
#pragma unroll
    for (int j = 0; j < 4; ++j) {
      const int gn = n0 + wn + j * 16 + fr16;
      pc1[((size_t)b * ESN + gn) * 32 + rblk] = cs1[j];
      pc2[((size_t)b * ESN + gn) * 32 + rblk] = cs2[j];
    }
  }
  // ET transpose: two 64-column chunks via LDS (gemm LDS is dead post-barrier)
#pragma unroll
  for (int h = 0; h < 2; ++h) {
    if ((wn >> 6) == h) {
#pragma unroll
      for (int i = 0; i < 4; ++i)
#pragma unroll
        for (int j = 0; j < 4; ++j) {
          ushort4 pk;
          pk.x = f2bf(expf(acc[i][j][0]));
          pk.y = f2bf(expf(acc[i][j][1]));
          pk.z = f2bf(expf(acc[i][j][2]));
          pk.w = f2bf(expf(acc[i][j][3]));
          *(ushort4*)(LDS + (j * 16 + fr16) * 132 + wm + i * 16 + r4) = pk;
        }
    }
    __syncthreads();
#pragma unroll
    for (int p = 0; p < 4; ++p) {
      const int nl = p * 16 + (t >> 4);
      const int ml = (t & 15) * 8;
      int4 v = *(const int4*)(LDS + nl * 132 + ml);
      *(int4*)(ET + ((size_t)b * ESN + n0 + h * 64 + nl) * NT + m0 + ml) = v;
    }
    __syncthreads();
  }
}

__global__ __launch_bounds__(256) void k_slotin_mfma(const unsigned short* __restrict__ ET,
    const unsigned short* __restrict__ XT, const float* __restrict__ cinv,
    unsigned short* __restrict__ SI) {
  __shared__ unsigned short LDS[16384];
  ACC_INIT();
  const int b = blockIdx.z, m0 = blockIdx.x * 128, n0 = blockIdx.y * 128;
  gemm_core(ET + ((size_t)b * ESN + m0) * NT, XT + ((size_t)b * DD + n0) * NT, NT, LDS, acc);
  GEMM_EPI_VARS();
#pragma unroll
  for (int i = 0; i < 4; ++i)
#pragma unroll
    for (int j = 0; j < 4; ++j) {
      const int gmb = m0 + wm + i * 16 + r4;
      const int gn = n0 + wn + j * 16 + fr16;
#pragma unroll
      for (int r = 0; r < 4; ++r)
        SI[((size_t)b * ESN + gmb + r) * DD + gn] = f2bf(acc[i][j][r] * cinv[b * ESN + gmb + r]);
    }
}

__global__ __launch_bounds__(256) void k_ffn1_mfma(const unsigned short* __restrict__ SI,
    const unsigned short* __restrict__ w1b, const float* __restrict__ b1,
    unsigned short* __restrict__ H1) {
  __shared__ unsigned short LDS[16384];
  ACC_INIT();
  const int z = blockIdx.z, b = z >> 3, e = z & 7;
  const int m0 = blockIdx.x * 128, n0 = blockIdx.y * 128;
  gemm_core(SI + ((size_t)b * ESN + e * SS + m0) * DD, w1b + ((size_t)e * HH + n0) * DD,
            DD, LDS, acc);
  GEMM_EPI_VARS();
#pragma unroll
  for (int i = 0; i < 4; ++i)
#pragma unroll
    for (int j = 0; j < 4; ++j) {
      const int gmb = m0 + wm + i * 16 + r4;
      const int gn = n0 + wn + j * 16 + fr16;
      const float bias = b1[e * HH + gn];
#pragma unroll
      for (int r = 0; r < 4; ++r)
        H1[((size_t)(b * EE + e) * SS + gmb + r) * HH + gn] = f2bf(gelu_f(acc[i][j][r] + bias));
    }
}

// ffn2 -> SOT[d][c] via chunked LDS transpose (coalesced 256B rows)
__global__ __launch_bounds__(256) void k_ffn2_mfma(const unsigned short* __restrict__ H1,
    const unsigned short* __restrict__ w2b, const float* __restrict__ b2,
    unsigned short* __restrict__ SOT) {
  __shared__ unsigned short LDS[16384];
  ACC_INIT();
  const int z = blockIdx.z, b = z >> 3, e = z & 7;
  const int m0 = blockIdx.x * 128, n0 = blockIdx.y * 128;   // m: s within expert, n: d
  gemm_core(H1 + ((size_t)(b * EE + e) * SS + m0) * HH, w2b + ((size_t)e * DD + n0) * HH,
            HH, LDS, acc);
  GEMM_EPI_VARS();
  const int t = threadIdx.x;
#pragma unroll
  for (int h = 0; h < 2; ++h) {
    if ((wn >> 6) == h) {
#pragma unroll
      for (int i = 0; i < 4; ++i)
#pragma unroll
        for (int j = 0; j < 4; ++j) {
          const float bias = b2[e * DD + n0 + wn + j * 16 + fr16];
          ushort4 pk;
          pk.x = f2bf(acc[i][j][0] + bias);
          pk.y = f2bf(acc[i][j][1] + bias);
          pk.z = f2bf(acc[i][j][2] + bias);
          pk.w = f2bf(acc[i][j][3] + bias);
          *(ushort4*)(LDS + (j * 16 + fr16) * 132 + wm + i * 16 + r4) = pk;
        }
    }
    __syncthreads();
#pragma unroll
    for (int p = 0; p < 4; ++p) {
      const int dl = p * 16 + (t >> 4);
      const int ml = (t & 15) * 8;
      int4 v = *(const int4*)(LDS + dl * 132 + ml);
      *(int4*)(SOT + ((size_t)b * DD + n0 + h * 64 + dl) * ESN + e * SS + m0 + ml) = v;
    }
    __syncthreads();
  }
}

__global__ __launch_bounds__(256) void k_img_mfma(const unsigned short* __restrict__ E16,
    const unsigned short* __restrict__ SOT, const float* __restrict__ rinv,
    float* __restrict__ out) {
  __shared__ unsigned short LDS[16384];
  ACC_INIT();
  const int b = blockIdx.z, m0 = blockIdx.x * 128, n0 = blockIdx.y * 128;
  gemm_core(E16 + ((size_t)b * NT + m0) * ESN, SOT + ((size_t)b * DD + n0) * ESN,
            ESN, LDS, acc);
  GEMM_EPI_VARS();
#pragma unroll
  for (int i = 0; i < 4; ++i)
#pragma unroll
    for (int j = 0; j < 4; ++j) {
      const int gmb = m0 + wm + i * 16 + r4;
      const int gn = n0 + wn + j * 16 + fr16;
#pragma unroll
      for (int r = 0; r < 4; ++r)
        out[((size_t)b * SEQ + 1 + gmb + r) * DD + gn] = acc[i][j][r] * rinv[b * NT + gmb + r];
    }
}

// -------- packing --------
__global__ __launch_bounds__(256) void k_xnf(const float* __restrict__ x, float* __restrict__ xnf) {
  const int wid = blockIdx.x * 4 + (threadIdx.x >> 6);
  const int lane = threadIdx.x & 63;
  const int b = wid >> 11;
  const float* row = x + ((size_t)b * SEQ + 1 + (wid & (NT - 1))) * DD;
  float s = 0.f;
#pragma unroll
  for (int k = 0; k < DD / 64; ++k) { const float v = row[lane + k * 64]; s = fmaf(v, v, s); }
  s = wave_sum(s);
  if (lane == 0) xnf[wid] = 1.0f / fmaxf(sqrtf(s), 1e-12f);
}

__global__ __launch_bounds__(256) void k_munf(const float* __restrict__ mu,
    const float* __restrict__ scale, float* __restrict__ munf) {
  __shared__ float part[4][64];
  const int c0 = blockIdx.x * 64;
  const int ci = threadIdx.x & 63, dg = threadIdx.x >> 6;
  float s = 0.f;
  for (int d = dg; d < DD; d += 4) { const float v = mu[(size_t)d * ESN + c0 + ci]; s = fmaf(v, v, s); }
  part[dg][ci] = s;
  __syncthreads();
  if (threadIdx.x < 64) {
    const float t = part[0][ci] + part[1][ci] + part[2][ci] + part[3][ci];
    munf[c0 + ci] = scale[0] / fmaxf(sqrtf(t), 1e-12f);
  }
}

__global__ __launch_bounds__(256) void k_pack_x(const float* __restrict__ x,
    const float* __restrict__ xnf, unsigned short* __restrict__ Xb,
    unsigned short* __restrict__ XT) {
  __shared__ unsigned short tile[64][72];
  const int b = blockIdx.z, n0 = blockIdx.x * 64, d0 = blockIdx.y * 64;
  const int t = threadIdx.x, tr = t >> 2, tc = (t & 3) * 16;
  const float* s = x + ((size_t)b * SEQ + 1 + n0 + tr) * DD + d0 + tc;
  const float xs = xnf[b * NT + n0 + tr];
  unsigned short tmp[16];
#pragma unroll
  for (int j = 0; j < 16; j += 4) {
    float4 v = *(const float4*)(s + j);
    tmp[j] = f2bf(v.x * xs); tmp[j + 1] = f2bf(v.y * xs);
    tmp[j + 2] = f2bf(v.z * xs); tmp[j + 3] = f2bf(v.w * xs);
  }
  *(int4*)&tile[tr][tc] = *(int4*)tmp;
  *(int4*)&tile[tr][tc + 8] = *(int4*)(tmp + 8);
  unsigned short* xb = Xb + ((size_t)b * NT + n0 + tr) * DD + d0 + tc;
  *(int4*)xb = *(int4*)tmp;
  *(int4*)(xb + 8) = *(int4*)(tmp + 8);
  __syncthreads();
  unsigned short* d = XT + ((size_t)b * DD + d0 + tr) * NT + n0 + tc;
#pragma unroll
  for (int j = 0; j < 16; ++j) tmp[j] = tile[tc + j][tr];
  *(int4*)d = *(int4*)tmp;
  *(int4*)(d + 8) = *(int4*)(tmp + 8);
}

__global__ __launch_bounds__(256) void k_pack_mu(const float* __restrict__ mu,
    const float* __restrict__ munf, unsigned short* __restrict__ MT) {
  __shared__ unsigned short tile[64][72];
  const int d0 = blockIdx.x * 64, c0 = blockIdx.y * 64;
  const int t = threadIdx.x, tr = t >> 2, tc = (t & 3) * 16;
  const float* s = mu + (size_t)(d0 + tr) * ESN + c0 + tc;
  unsigned short tmp[16];
#pragma unroll
  for (int j = 0; j < 16; j += 4) {
    float4 v = *(const float4*)(s + j);
    tmp[j] = f2bf(v.x * munf[c0 + tc + j]);
    tmp[j + 1] = f2bf(v.y * munf[c0 + tc + j + 1]);
    tmp[j + 2] = f2bf(v.z * munf[c0 + tc + j + 2]);
    tmp[j + 3] = f2bf(v.w * munf[c0 + tc + j + 3]);
  }
  *(int4*)&tile[tr][tc] = *(int4*)tmp;
  *(int4*)&tile[tr][tc + 8] = *(int4*)(tmp + 8);
  __syncthreads();
  unsigned short* d = MT + (size_t)(c0 + tr) * DD + d0 + tc;
#pragma unroll
  for (int j = 0; j < 16; ++j) tmp[j] = tile[tc + j][tr];
  *(int4*)d = *(int4*)tmp;
  *(int4*)(d + 8) = *(int4*)(tmp + 8);
}

__global__ __launch_bounds__(256) void k_packw(const float* __restrict__ w,
    unsigned short* __restrict__ o, int n4) {
  const int i = blockIdx.x * 256 + threadIdx.x;
  if (i < n4) {
    float4 v = ((const float4*)w)[i];
    ushort4 u;
    u.x = f2bf(v.x); u.y = f2bf(v.y); u.z = f2bf(v.z); u.w = f2bf(v.w);
    ((ushort4*)o)[i] = u;
  }
}

// -------- tiny stat reductions over partials --------
__global__ __launch_bounds__(256) void k_rowred(const float* __restrict__ pr1,
    const float* __restrict__ pr2, const unsigned short* __restrict__ E16,
    float* __restrict__ rinv, float* __restrict__ t_r2, float* __restrict__ t_dr) {
  const int wid = blockIdx.x * 256 + threadIdx.x;  // b*NT + n
  float s1 = 0.f, s2 = 0.f;
#pragma unroll
  for (int k = 0; k < 32; ++k) {
    s1 += pr1[(size_t)wid * 32 + k];
    s2 += pr2[(size_t)wid * 32 + k];
  }
  const int n = wid & (NT - 1);
  const float ri = 1.0f / s1;
  rinv[wid] = ri;
  const float r2 = 1.0f / (s2 * ri * ri + 1e-9f);
  t_r2[wid] = r2;
  t_dr[wid] = bf2f(E16[(size_t)wid * ESN + n]) * ri * r2;
}

__global__ __launch_bounds__(256) void k_colred(const float* __restrict__ pc1,
    const float* __restrict__ pc2, float* __restrict__ cinv,
    float* __restrict__ t_rs2, float* __restrict__ t_sd) {
  const int wid = blockIdx.x * 256 + threadIdx.x;  // b*ESN + c
  float s1 = 0.f, s2 = 0.f;
#pragma unroll
  for (int k = 0; k < 32; ++k) {
    s1 += pc1[(size_t)wid * 32 + k];
    s2 += pc2[(size_t)wid * 32 + k];
  }
  const float ci = 1.0f / s1;
  cinv[wid] = ci;
  const float rs2 = 1.0f / (s2 * ci * ci + 1e-9f);
  t_rs2[wid] = rs2;
  const int c = wid & (ESN - 1);
  t_sd[wid] = ((c % 257) == 0) ? rs2 : 0.f;
}

// -------- cls path --------
__global__ __launch_bounds__(256) void k_clsA(const float* __restrict__ x,
    const float* __restrict__ w1, const float* __restrict__ b1, float* __restrict__ clsh) {
  const int wid = blockIdx.x * 4 + (threadIdx.x >> 6);
  const int lane = threadIdx.x & 63;
  const int b = wid >> 9, h = wid & (HH - 1);
  const float* xr = x + (size_t)b * SEQ * DD;
  const float* wr = w1 + (size_t)h * DD;
  float s = 0.f;
#pragma unroll
  for (int k = 0; k < DD / 64; ++k) s = fmaf(xr[lane + k * 64], wr[lane + k * 64], s);
  s = wave_sum(s);
  if (lane == 0) clsh[wid] = gelu_f(s + b1[h]);
}

__global__ __launch_bounds__(256) void k_clsB(const float* __restrict__ clsh,
    const float* __restrict__ w2, const float* __restrict__ b2, float* __restrict__ out) {
  const int wid = blockIdx.x * 4 + (threadIdx.x >> 6);
  const int lane = threadIdx.x & 63;
  const int b = wid >> 10, d = wid & (DD - 1);
  const float* hr = clsh + (size_t)b * HH;
  const float* wr = w2 + (size_t)d * HH;
  float s = 0.f;
#pragma unroll
  for (int k = 0; k < HH / 64; ++k) s = fmaf(hr[lane + k * 64], wr[lane + k * 64], s);
  s = wave_sum(s);
  if (lane == 0) out[(size_t)b * SEQ * DD + d] = s + b2[d];
}

__global__ __launch_bounds__(256) void k_metrics(const float* __restrict__ t_r2,
    const float* __restrict__ t_dr, const float* __restrict__ t_rs2,
    const float* __restrict__ t_sd, float* __restrict__ out) {
  __shared__ float sm[256];
  const int tid = threadIdx.x;
  float a = 0.f, b = 0.f, c = 0.f, d = 0.f;
  for (int i = tid; i < BB * NT; i += 256) { a += t_r2[i]; b += t_dr[i]; }
  for (int i = tid; i < BB * ESN; i += 256) { c += t_rs2[i]; d += t_sd[i]; }
  float vals[4] = {a, b, c, d};
  float res[4];
#pragma unroll
  for (int v = 0; v < 4; ++v) {
    sm[tid] = vals[v];
    __syncthreads();
    for (int s = 128; s > 0; s >>= 1) {
      if (tid < s) sm[tid] += sm[tid + s];
      __syncthreads();
    }
    res[v] = sm[0];
    __syncthreads();
  }
  if (tid == 0) {
    out[(size_t)BB * SEQ * DD] = (res[0] - res[1]) / 33538048.0f;
    out[(size_t)BB * SEQ * DD + 1] = (res[2] - res[3]) / 33538048.0f;
  }
}

extern "C" void kernel_launch(void* const* d_in, const int* in_sizes, int n_in,
                              void* d_out, int out_size, void* d_ws, size_t ws_size,
                              hipStream_t stream) {
  const float* x      = (const float*)d_in[0];
  const float* mu     = (const float*)d_in[1];
  const float* scale  = (const float*)d_in[2];
  const float* cls_w1 = (const float*)d_in[3];
  const float* cls_b1 = (const float*)d_in[4];
  const float* cls_w2 = (const float*)d_in[5];
  const float* cls_b2 = (const float*)d_in[6];
  const float* w1     = (const float*)d_in[7];
  const float* b1     = (const float*)d_in[8];
  const float* w2     = (const float*)d_in[9];
  const float* b2     = (const float*)d_in[10];
  float* out = (float*)d_out;

  // workspace plan (bytes), aliasing by lifetime:
  char* W = (char*)d_ws;
  unsigned short* XT  = (unsigned short*)(W);              // 32MB; H1 aliases after slotin
  unsigned short* Xb  = (unsigned short*)(W + 33554432);   // 32MB; SOT aliases after logits
  unsigned short* MT  = (unsigned short*)(W + 67108864);   //  4MB
  unsigned short* E16 = (unsigned short*)(W + 71303168);   // 64MB (lives until img)
  unsigned short* ET  = (unsigned short*)(W + 138412032);  // 64MB; w1b/w2b alias after slotin
  unsigned short* SI  = (unsigned short*)(W + 205520896);  // 32MB; partials alias before slotin
  unsigned short* H1  = (unsigned short*)(W);              // 16MB (alias XT)
  unsigned short* SOT = (unsigned short*)(W + 33554432);   // 32MB (alias Xb)
  unsigned short* w1b = (unsigned short*)(W + 138412032);  //  8MB (alias ET)
  unsigned short* w2b = (unsigned short*)(W + 146800640);  //  8MB (alias ET)
  // stat partials live in SI's region (dead until slotin writes SI)
  float* pr1 = (float*)(W + 205520896);                    // 2MB
  float* pr2 = (float*)(W + 207618048);                    // 2MB
  float* pc1 = (float*)(W + 209715200);                    // 2MB
  float* pc2 = (float*)(W + 211812352);                    // 2MB
  float* F = (float*)(W + 239075328);
  float* xnf   = F;
  float* munf  = F + 16384;
  float* rinv  = F + 18432;
  float* t_r2  = F + 34816;
  float* t_dr  = F + 51200;
  float* cinv  = F + 67584;
  float* t_rs2 = F + 83968;
  float* t_sd  = F + 100352;
  float* clsh  = F + 116736;

  k_xnf<<<dim3(BB * NT / 4), 256, 0, stream>>>(x, xnf);
  k_munf<<<dim3(ESN / 64), 256, 0, stream>>>(mu, scale, munf);
  k_pack_x<<<dim3(NT / 64, DD / 64, BB), 256, 0, stream>>>(x, xnf, Xb, XT);
  k_pack_mu<<<dim3(DD / 64, ESN / 64), 256, 0, stream>>>(mu, munf, MT);
  k_logits_mfma<<<dim3(NT / 128, ESN / 128, BB), 256, 0, stream>>>(Xb, MT, E16, ET,
                                                                   pr1, pr2, pc1, pc2);
  k_rowred<<<dim3(BB * NT / 256), 256, 0, stream>>>(pr1, pr2, E16, rinv, t_r2, t_dr);
  k_colred<<<dim3(BB * ESN / 256), 256, 0, stream>>>(pc1, pc2, cinv, t_rs2, t_sd);
  k_slotin_mfma<<<dim3(ESN / 128, DD / 128, BB), 256, 0, stream>>>(ET, XT, cinv, SI);
  k_packw<<<dim3(EE * HH * DD / 4 / 256), 256, 0, stream>>>(w1, w1b, EE * HH * DD / 4);
  k_packw<<<dim3(EE * DD * HH / 4 / 256), 256, 0, stream>>>(w2, w2b, EE * DD * HH / 4);
  k_ffn1_mfma<<<dim3(SS / 128, HH / 128, BB * EE), 256, 0, stream>>>(SI, w1b, b1, H1);
  k_ffn2_mfma<<<dim3(SS / 128, DD / 128, BB * EE), 256, 0, stream>>>(H1, w2b, b2, SOT);
  k_img_mfma<<<dim3(NT / 128, DD / 128, BB), 256, 0, stream>>>(E16, SOT, rinv, out);
  k_clsA<<<dim3(BB * HH / 4), 256, 0, stream>>>(x, cls_w1, cls_b1, clsh);
  k_clsB<<<dim3(BB * DD / 4), 256, 0, stream>>>(clsh, cls_w2, cls_b2, out);
  k_metrics<<<1, 256, 0, stream>>>(t_r2, t_dr, t_rs2, t_sd, out);
}

// Round 8
// 659.197 us; speedup vs baseline: 1.0401x; 1.0401x over previous
//
#include <hip/hip_runtime.h>
#include <math.h>

// Shapes (fixed)
#define BB 8
#define SEQ 2049
#define NT 2048
#define DD 1024
#define EE 8
#define SS 256
#define ESN 2048
#define HH 512

typedef __bf16 bf16x8 __attribute__((ext_vector_type(8)));
typedef float f32x4 __attribute__((ext_vector_type(4)));

__device__ __forceinline__ float gelu_f(float v) {
  return 0.5f * v * (1.0f + erff(v * 0.70710678118654752440f));
}
__device__ __forceinline__ float wave_sum(float v) {
#pragma unroll
  for (int off = 1; off < 64; off <<= 1) v += __shfl_xor(v, off);
  return v;
}
__device__ __forceinline__ unsigned short f2bf(float f) {
  unsigned int u = __float_as_uint(f);
  u = (u + 0x7fffu + ((u >> 16) & 1u)) >> 16;
  return (unsigned short)u;
}
__device__ __forceinline__ float bf2f(unsigned short h) {
  return __uint_as_float(((unsigned int)h) << 16);
}

// async 16B/lane global->LDS stage; lbase is wave-uniform, HW adds lane*16.
__device__ __forceinline__ void stage16(const unsigned short* g, unsigned short* lbase, int lane) {
#if __has_builtin(__builtin_amdgcn_global_load_lds)
  __builtin_amdgcn_global_load_lds((const __attribute__((address_space(1))) void*)g,
                                   (__attribute__((address_space(3))) void*)lbase, 16, 0, 0);
#else
  *(int4*)(lbase + lane * 8) = *(const int4*)g;
#endif
}

// ---- bf16 gemm_bt core (round-2/5 known-good): C[128x128]=A[m][k]*B[n][k]^T ----
// 256 threads = 4 waves (2x2 of 64x64). LDS tiles [128][32] bf16 linear.
// Single-buffered BK=32: stage -> barrier -> compute -> barrier.
__device__ __forceinline__ void gemm_core(const unsigned short* __restrict__ A,
                                          const unsigned short* __restrict__ B,
                                          int K, unsigned short* As, unsigned short* Bs,
                                          f32x4 acc[4][4]) {
  const int t = threadIdx.x;
  const int lane = t & 63, wave = t >> 6;
  const int srow = t >> 2, scol = (t & 3) * 8;
  const int fr = lane & 15, fk = (lane >> 4) * 8;
  const int wm = (wave >> 1) * 64, wn = (wave & 1) * 64;
  const unsigned short* a0 = A + (size_t)srow * K + scol;
  const unsigned short* a1 = A + (size_t)(srow + 64) * K + scol;
  const unsigned short* b0 = B + (size_t)srow * K + scol;
  const unsigned short* b1 = B + (size_t)(srow + 64) * K + scol;
  unsigned short* lA0 = As + wave * 512;
  unsigned short* lA1 = As + 2048 + wave * 512;
  unsigned short* lB0 = Bs + wave * 512;
  unsigned short* lB1 = Bs + 2048 + wave * 512;
  for (int k0 = 0; k0 < K; k0 += 32) {
    stage16(a0 + k0, lA0, lane);
    stage16(a1 + k0, lA1, lane);
    stage16(b0 + k0, lB0, lane);
    stage16(b1 + k0, lB1, lane);
    __syncthreads();  // drains vmcnt: staged tiles visible
    bf16x8 af[4], bfr[4];
#pragma unroll
    for (int i = 0; i < 4; ++i)
      af[i] = *(const bf16x8*)(As + (wm + i * 16 + fr) * 32 + fk);
#pragma unroll
    for (int j = 0; j < 4; ++j)
      bfr[j] = *(const bf16x8*)(Bs + (wn + j * 16 + fr) * 32 + fk);
#pragma unroll
    for (int i = 0; i < 4; ++i)
#pragma unroll
      for (int j = 0; j < 4; ++j)
        acc[i][j] = __builtin_amdgcn_mfma_f32_16x16x32_bf16(af[i], bfr[j], acc[i][j], 0, 0, 0);
    __syncthreads();  // all reads done before next stage overwrites
  }
}

#define ACC_INIT()                                        \
  f32x4 acc[4][4];                                        \
  _Pragma("unroll") for (int i = 0; i < 4; ++i)           \
  _Pragma("unroll") for (int j = 0; j < 4; ++j)           \
  _Pragma("unroll") for (int r = 0; r < 4; ++r) acc[i][j][r] = 0.f;

#define GEMM_EPI_VARS()                                   \
  const int lane = threadIdx.x & 63, wave = threadIdx.x >> 6; \
  const int wm = (wave >> 1) * 64, wn = (wave & 1) * 64;  \
  const int fr16 = lane & 15, r4 = (lane >> 4) << 2;

// logits -> E16[n][c] direct + row/col softmax-stat partials + ET[c][n] via LDS transpose.
__global__ __launch_bounds__(256) void k_logits_mfma(const unsigned short* __restrict__ Xb,
    const unsigned short* __restrict__ MT, unsigned short* __restrict__ E16,
    unsigned short* __restrict__ ET, float* __restrict__ pr1, float* __restrict__ pr2,
    float* __restrict__ pc1, float* __restrict__ pc2) {
  __shared__ unsigned short LDS[8448];
  ACC_INIT();
  const int b = blockIdx.z, m0 = blockIdx.x * 128, n0 = blockIdx.y * 128;
  gemm_core(Xb + ((size_t)b * NT + m0) * DD, MT + (size_t)n0 * DD, DD, LDS, LDS + 4096, acc);
  GEMM_EPI_VARS();
  const int t = threadIdx.x;
  unsigned short* o = E16 + (size_t)b * NT * ESN;
  const int cblk = (n0 >> 6) + (wn >> 6);
  const int rblk = (m0 >> 6) + (wm >> 6);
  float cs1[4] = {0.f, 0.f, 0.f, 0.f}, cs2[4] = {0.f, 0.f, 0.f, 0.f};
#pragma unroll
  for (int i = 0; i < 4; ++i) {
    const int gmb = m0 + wm + i * 16 + r4;
    float rs1[4] = {0.f, 0.f, 0.f, 0.f}, rs2[4] = {0.f, 0.f, 0.f, 0.f};
#pragma unroll
    for (int j = 0; j < 4; ++j) {
      const int gn = n0 + wn + j * 16 + fr16;
#pragma unroll
      for (int r = 0; r < 4; ++r) {
        const float ev = expf(acc[i][j][r]);
        o[(size_t)(gmb + r) * ESN + gn] = f2bf(ev);
        rs1[r] += ev; rs2[r] = fmaf(ev, ev, rs2[r]);
        cs1[j] += ev; cs2[j] = fmaf(ev, ev, cs2[j]);
      }
    }
    // row partials: reduce across the 16 column-lanes (fr16)
#pragma unroll
    for (int r = 0; r < 4; ++r) {
#pragma unroll
      for (int m = 1; m < 16; m <<= 1) {
        rs1[r] += __shfl_xor(rs1[r], m);
        rs2[r] += __shfl_xor(rs2[r], m);
      }
    }
    if (fr16 == 0) {
#pragma unroll
      for (int r = 0; r < 4; ++r) {
        pr1[((size_t)b * NT + gmb + r) * 32 + cblk] = rs1[r];
        pr2[((size_t)b * NT + gmb + r) * 32 + cblk] = rs2[r];
      }
    }
  }
  // col partials: lanes sharing fr16 (bits 4-5) hold disjoint 16-row pieces of
  // the wave's 64-row block -> reduce across lane^16/^32, write once (race fix).
#pragma unroll
  for (int j = 0; j < 4; ++j) {
    cs1[j] += __shfl_xor(cs1[j], 16);
    cs2[j] += __shfl_xor(cs2[j], 16);
    cs1[j] += __shfl_xor(cs1[j], 32);
    cs2[j] += __shfl_xor(cs2[j], 32);
  }
  if (lane < 16) {
#pragma unroll
    for (int j = 0; j < 4; ++j) {
      const int gn = n0 + wn + j * 16 + fr16;
      pc1[((size_t)b * ESN + gn) * 32 + rblk] = cs1[j];
      pc2[((size_t)b * ESN + gn) * 32 + rblk] = cs2[j];
    }
  }
  // ET transpose: two 64-column chunks via LDS (gemm LDS dead post-barrier)
#pragma unroll
  for (int h = 0; h < 2; ++h) {
    if ((wn >> 6) == h) {
#pragma unroll
      for (int i = 0; i < 4; ++i)
#pragma unroll
        for (int j = 0; j < 4; ++j) {
          ushort4 pk;
          pk.x = f2bf(expf(acc[i][j][0]));
          pk.y = f2bf(expf(acc[i][j][1]));
          pk.z = f2bf(expf(acc[i][j][2]));
          pk.w = f2bf(expf(acc[i][j][3]));
          *(ushort4*)(LDS + (j * 16 + fr16) * 132 + wm + i * 16 + r4) = pk;
        }
    }
    __syncthreads();
#pragma unroll
    for (int p = 0; p < 4; ++p) {
      const int nl = p * 16 + (t >> 4);
      const int ml = (t & 15) * 8;
      int4 v = *(const int4*)(LDS + nl * 132 + ml);
      *(int4*)(ET + ((size_t)b * ESN + n0 + h * 64 + nl) * NT + m0 + ml) = v;
    }
    __syncthreads();
  }
}

__global__ __launch_bounds__(256) void k_slotin_mfma(const unsigned short* __restrict__ ET,
    const unsigned short* __restrict__ XT, const float* __restrict__ cinv,
    unsigned short* __restrict__ SI) {
  __shared__ unsigned short LDS[8192];
  ACC_INIT();
  const int b = blockIdx.z, m0 = blockIdx.x * 128, n0 = blockIdx.y * 128;
  gemm_core(ET + ((size_t)b * ESN + m0) * NT, XT + ((size_t)b * DD + n0) * NT, NT,
            LDS, LDS + 4096, acc);
  GEMM_EPI_VARS();
#pragma unroll
  for (int i = 0; i < 4; ++i)
#pragma unroll
    for (int j = 0; j < 4; ++j) {
      const int gmb = m0 + wm + i * 16 + r4;
      const int gn = n0 + wn + j * 16 + fr16;
#pragma unroll
      for (int r = 0; r < 4; ++r)
        SI[((size_t)b * ESN + gmb + r) * DD + gn] = f2bf(acc[i][j][r] * cinv[b * ESN + gmb + r]);
    }
}

__global__ __launch_bounds__(256) void k_ffn1_mfma(const unsigned short* __restrict__ SI,
    const unsigned short* __restrict__ w1b, const float* __restrict__ b1,
    unsigned short* __restrict__ H1) {
  __shared__ unsigned short LDS[8192];
  ACC_INIT();
  const int z = blockIdx.z, b = z >> 3, e = z & 7;
  const int m0 = blockIdx.x * 128, n0 = blockIdx.y * 128;
  gemm_core(SI + ((size_t)b * ESN + e * SS + m0) * DD, w1b + ((size_t)e * HH + n0) * DD,
            DD, LDS, LDS + 4096, acc);
  GEMM_EPI_VARS();
#pragma unroll
  for (int i = 0; i < 4; ++i)
#pragma unroll
    for (int j = 0; j < 4; ++j) {
      const int gmb = m0 + wm + i * 16 + r4;
      const int gn = n0 + wn + j * 16 + fr16;
      const float bias = b1[e * HH + gn];
#pragma unroll
      for (int r = 0; r < 4; ++r)
        H1[((size_t)(b * EE + e) * SS + gmb + r) * HH + gn] = f2bf(gelu_f(acc[i][j][r] + bias));
    }
}

// ffn2 -> SOT[d][c] via chunked LDS transpose (coalesced 256B rows)
__global__ __launch_bounds__(256) void k_ffn2_mfma(const unsigned short* __restrict__ H1,
    const unsigned short* __restrict__ w2b, const float* __restrict__ b2,
    unsigned short* __restrict__ SOT) {
  __shared__ unsigned short LDS[8448];
  ACC_INIT();
  const int z = blockIdx.z, b = z >> 3, e = z & 7;
  const int m0 = blockIdx.x * 128, n0 = blockIdx.y * 128;   // m: s within expert, n: d
  gemm_core(H1 + ((size_t)(b * EE + e) * SS + m0) * HH, w2b + ((size_t)e * DD + n0) * HH,
            HH, LDS, LDS + 4096, acc);
  GEMM_EPI_VARS();
  const int t = threadIdx.x;
#pragma unroll
  for (int h = 0; h < 2; ++h) {
    if ((wn >> 6) == h) {
#pragma unroll
      for (int i = 0; i < 4; ++i)
#pragma unroll
        for (int j = 0; j < 4; ++j) {
          const float bias = b2[e * DD + n0 + wn + j * 16 + fr16];
          ushort4 pk;
          pk.x = f2bf(acc[i][j][0] + bias);
          pk.y = f2bf(acc[i][j][1] + bias);
          pk.z = f2bf(acc[i][j][2] + bias);
          pk.w = f2bf(acc[i][j][3] + bias);
          *(ushort4*)(LDS + (j * 16 + fr16) * 132 + wm + i * 16 + r4) = pk;
        }
    }
    __syncthreads();
#pragma unroll
    for (int p = 0; p < 4; ++p) {
      const int dl = p * 16 + (t >> 4);
      const int ml = (t & 15) * 8;
      int4 v = *(const int4*)(LDS + dl * 132 + ml);
      *(int4*)(SOT + ((size_t)b * DD + n0 + h * 64 + dl) * ESN + e * SS + m0 + ml) = v;
    }
    __syncthreads();
  }
}

__global__ __launch_bounds__(256) void k_img_mfma(const unsigned short* __restrict__ E16,
    const unsigned short* __restrict__ SOT, const float* __restrict__ rinv,
    float* __restrict__ out) {
  __shared__ unsigned short LDS[8192];
  ACC_INIT();
  const int b = blockIdx.z, m0 = blockIdx.x * 128, n0 = blockIdx.y * 128;
  gemm_core(E16 + ((size_t)b * NT + m0) * ESN, SOT + ((size_t)b * DD + n0) * ESN,
            ESN, LDS, LDS + 4096, acc);
  GEMM_EPI_VARS();
#pragma unroll
  for (int i = 0; i < 4; ++i)
#pragma unroll
    for (int j = 0; j < 4; ++j) {
      const int gmb = m0 + wm + i * 16 + r4;
      const int gn = n0 + wn + j * 16 + fr16;
#pragma unroll
      for (int r = 0; r < 4; ++r)
        out[((size_t)b * SEQ + 1 + gmb + r) * DD + gn] = acc[i][j][r] * rinv[b * NT + gmb + r];
    }
}

// -------- packing --------
__global__ __launch_bounds__(256) void k_xnf(const float* __restrict__ x, float* __restrict__ xnf) {
  const int wid = blockIdx.x * 4 + (threadIdx.x >> 6);
  const int lane = threadIdx.x & 63;
  const int b = wid >> 11;
  const float* row = x + ((size_t)b * SEQ + 1 + (wid & (NT - 1))) * DD;
  float s = 0.f;
#pragma unroll
  for (int k = 0; k < DD / 64; ++k) { const float v = row[lane + k * 64]; s = fmaf(v, v, s); }
  s = wave_sum(s);
  if (lane == 0) xnf[wid] = 1.0f / fmaxf(sqrtf(s), 1e-12f);
}

__global__ __launch_bounds__(256) void k_munf(const float* __restrict__ mu,
    const float* __restrict__ scale, float* __restrict__ munf) {
  __shared__ float part[4][64];
  const int c0 = blockIdx.x * 64;
  const int ci = threadIdx.x & 63, dg = threadIdx.x >> 6;
  float s = 0.f;
  for (int d = dg; d < DD; d += 4) { const float v = mu[(size_t)d * ESN + c0 + ci]; s = fmaf(v, v, s); }
  part[dg][ci] = s;
  __syncthreads();
  if (threadIdx.x < 64) {
    const float t = part[0][ci] + part[1][ci] + part[2][ci] + part[3][ci];
    munf[c0 + ci] = scale[0] / fmaxf(sqrtf(t), 1e-12f);
  }
}

__global__ __launch_bounds__(256) void k_pack_x(const float* __restrict__ x,
    const float* __restrict__ xnf, unsigned short* __restrict__ Xb,
    unsigned short* __restrict__ XT) {
  __shared__ unsigned short tile[64][72];
  const int b = blockIdx.z, n0 = blockIdx.x * 64, d0 = blockIdx.y * 64;
  const int t = threadIdx.x, tr = t >> 2, tc = (t & 3) * 16;
  const float* s = x + ((size_t)b * SEQ + 1 + n0 + tr) * DD + d0 + tc;
  const float xs = xnf[b * NT + n0 + tr];
  unsigned short tmp[16];
#pragma unroll
  for (int j = 0; j < 16; j += 4) {
    float4 v = *(const float4*)(s + j);
    tmp[j] = f2bf(v.x * xs); tmp[j + 1] = f2bf(v.y * xs);
    tmp[j + 2] = f2bf(v.z * xs); tmp[j + 3] = f2bf(v.w * xs);
  }
  *(int4*)&tile[tr][tc] = *(int4*)tmp;
  *(int4*)&tile[tr][tc + 8] = *(int4*)(tmp + 8);
  unsigned short* xb = Xb + ((size_t)b * NT + n0 + tr) * DD + d0 + tc;
  *(int4*)xb = *(int4*)tmp;
  *(int4*)(xb + 8) = *(int4*)(tmp + 8);
  __syncthreads();
  unsigned short* d = XT + ((size_t)b * DD + d0 + tr) * NT + n0 + tc;
#pragma unroll
  for (int j = 0; j < 16; ++j) tmp[j] = tile[tc + j][tr];
  *(int4*)d = *(int4*)tmp;
  *(int4*)(d + 8) = *(int4*)(tmp + 8);
}

__global__ __launch_bounds__(256) void k_pack_mu(const float* __restrict__ mu,
    const float* __restrict__ munf, unsigned short* __restrict__ MT) {
  __shared__ unsigned short tile[64][72];
  const int d0 = blockIdx.x * 64, c0 = blockIdx.y * 64;
  const int t = threadIdx.x, tr = t >> 2, tc = (t & 3) * 16;
  const float* s = mu + (size_t)(d0 + tr) * ESN + c0 + tc;
  unsigned short tmp[16];
#pragma unroll
  for (int j = 0; j < 16; j += 4) {
    float4 v = *(const float4*)(s + j);
    tmp[j] = f2bf(v.x * munf[c0 + tc + j]);
    tmp[j + 1] = f2bf(v.y * munf[c0 + tc + j + 1]);
    tmp[j + 2] = f2bf(v.z * munf[c0 + tc + j + 2]);
    tmp[j + 3] = f2bf(v.w * munf[c0 + tc + j + 3]);
  }
  *(int4*)&tile[tr][tc] = *(int4*)tmp;
  *(int4*)&tile[tr][tc + 8] = *(int4*)(tmp + 8);
  __syncthreads();
  unsigned short* d = MT + (size_t)(c0 + tr) * DD + d0 + tc;
#pragma unroll
  for (int j = 0; j < 16; ++j) tmp[j] = tile[tc + j][tr];
  *(int4*)d = *(int4*)tmp;
  *(int4*)(d + 8) = *(int4*)(tmp + 8);
}

__global__ __launch_bounds__(256) void k_packw(const float* __restrict__ w,
    unsigned short* __restrict__ o, int n4) {
  const int i = blockIdx.x * 256 + threadIdx.x;
  if (i < n4) {
    float4 v = ((const float4*)w)[i];
    ushort4 u;
    u.x = f2bf(v.x); u.y = f2bf(v.y); u.z = f2bf(v.z); u.w = f2bf(v.w);
    ((ushort4*)o)[i] = u;
  }
}

// -------- tiny stat reductions over partials --------
__global__ __launch_bounds__(256) void k_rowred(const float* __restrict__ pr1,
    const float* __restrict__ pr2, const unsigned short* __restrict__ E16,
    float* __restrict__ rinv, float* __restrict__ t_r2, float* __restrict__ t_dr) {
  const int wid = blockIdx.x * 256 + threadIdx.x;  // b*NT + n
  float s1 = 0.f, s2 = 0.f;
#pragma unroll
  for (int k = 0; k < 32; ++k) {
    s1 += pr1[(size_t)wid * 32 + k];
    s2 += pr2[(size_t)wid * 32 + k];
  }
  const int n = wid & (NT - 1);
  const float ri = 1.0f / s1;
  rinv[wid] = ri;
  const float r2 = 1.0f / (s2 * ri * ri + 1e-9f);
  t_r2[wid] = r2;
  t_dr[wid] = bf2f(E16[(size_t)wid * ESN + n]) * ri * r2;
}

__global__ __launch_bounds__(256) void k_colred(const float* __restrict__ pc1,
    const float* __restrict__ pc2, float* __restrict__ cinv,
    float* __restrict__ t_rs2, float* __restrict__ t_sd) {
  const int wid = blockIdx.x * 256 + threadIdx.x;  // b*ESN + c
  float s1 = 0.f, s2 = 0.f;
#pragma unroll
  for (int k = 0; k < 32; ++k) {
    s1 += pc1[(size_t)wid * 32 + k];
    s2 += pc2[(size_t)wid * 32 + k];
  }
  const float ci = 1.0f / s1;
  cinv[wid] = ci;
  const float rs2 = 1.0f / (s2 * ci * ci + 1e-9f);
  t_rs2[wid] = rs2;
  const int c = wid & (ESN - 1);
  t_sd[wid] = ((c % 257) == 0) ? rs2 : 0.f;
}

// -------- cls path --------
__global__ __launch_bounds__(256) void k_clsA(const float* __restrict__ x,
    const float* __restrict__ w1, const float* __restrict__ b1, float* __restrict__ clsh) {
  const int wid = blockIdx.x * 4 + (threadIdx.x >> 6);
  const int lane = threadIdx.x & 63;
  const int b = wid >> 9, h = wid & (HH - 1);
  const float* xr = x + (size_t)b * SEQ * DD;
  const float* wr = w1 + (size_t)h * DD;
  float s = 0.f;
#pragma unroll
  for (int k = 0; k < DD / 64; ++k) s = fmaf(xr[lane + k * 64], wr[lane + k * 64], s);
  s = wave_sum(s);
  if (lane == 0) clsh[wid] = gelu_f(s + b1[h]);
}

__global__ __launch_bounds__(256) void k_clsB(const float* __restrict__ clsh,
    const float* __restrict__ w2, const float* __restrict__ b2, float* __restrict__ out) {
  const int wid = blockIdx.x * 4 + (threadIdx.x >> 6);
  const int lane = threadIdx.x & 63;
  const int b = wid >> 10, d = wid & (DD - 1);
  const float* hr = clsh + (size_t)b * HH;
  const float* wr = w2 + (size_t)d * HH;
  float s = 0.f;
#pragma unroll
  for (int k = 0; k < HH / 64; ++k) s = fmaf(hr[lane + k * 64], wr[lane + k * 64], s);
  s = wave_sum(s);
  if (lane == 0) out[(size_t)b * SEQ * DD + d] = s + b2[d];
}

__global__ __launch_bounds__(256) void k_metrics(const float* __restrict__ t_r2,
    const float* __restrict__ t_dr, const float* __restrict__ t_rs2,
    const float* __restrict__ t_sd, float* __restrict__ out) {
  __shared__ float sm[256];
  const int tid = threadIdx.x;
  float a = 0.f, b = 0.f, c = 0.f, d = 0.f;
  for (int i = tid; i < BB * NT; i += 256) { a += t_r2[i]; b += t_dr[i]; }
  for (int i = tid; i < BB * ESN; i += 256) { c += t_rs2[i]; d += t_sd[i]; }
  float vals[4] = {a, b, c, d};
  float res[4];
#pragma unroll
  for (int v = 0; v < 4; ++v) {
    sm[tid] = vals[v];
    __syncthreads();
    for (int s = 128; s > 0; s >>= 1) {
      if (tid < s) sm[tid] += sm[tid + s];
      __syncthreads();
    }
    res[v] = sm[0];
    __syncthreads();
  }
  if (tid == 0) {
    out[(size_t)BB * SEQ * DD] = (res[0] - res[1]) / 33538048.0f;
    out[(size_t)BB * SEQ * DD + 1] = (res[2] - res[3]) / 33538048.0f;
  }
}

extern "C" void kernel_launch(void* const* d_in, const int* in_sizes, int n_in,
                              void* d_out, int out_size, void* d_ws, size_t ws_size,
                              hipStream_t stream) {
  const float* x      = (const float*)d_in[0];
  const float* mu     = (const float*)d_in[1];
  const float* scale  = (const float*)d_in[2];
  const float* cls_w1 = (const float*)d_in[3];
  const float* cls_b1 = (const float*)d_in[4];
  const float* cls_w2 = (const float*)d_in[5];
  const float* cls_b2 = (const float*)d_in[6];
  const float* w1     = (const float*)d_in[7];
  const float* b1     = (const float*)d_in[8];
  const float* w2     = (const float*)d_in[9];
  const float* b2     = (const float*)d_in[10];
  float* out = (float*)d_out;

  // workspace plan (bytes), aliasing by lifetime:
  char* W = (char*)d_ws;
  unsigned short* XT  = (unsigned short*)(W);              // 32MB; H1 aliases after slotin
  unsigned short* Xb  = (unsigned short*)(W + 33554432);   // 32MB; SOT aliases after logits
  unsigned short* MT  = (unsigned short*)(W + 67108864);   //  4MB
  unsigned short* E16 = (unsigned short*)(W + 71303168);   // 64MB (lives until img)
  unsigned short* ET  = (unsigned short*)(W + 138412032);  // 64MB; w1b/w2b alias after slotin
  unsigned short* SI  = (unsigned short*)(W + 205520896);  // 32MB; partials alias before slotin
  unsigned short* H1  = (unsigned short*)(W);              // 16MB (alias XT)
  unsigned short* SOT = (unsigned short*)(W + 33554432);   // 32MB (alias Xb)
  unsigned short* w1b = (unsigned short*)(W + 138412032);  //  8MB (alias ET)
  unsigned short* w2b = (unsigned short*)(W + 146800640);  //  8MB (alias ET)
  // stat partials live in SI's region (dead until slotin writes SI)
  float* pr1 = (float*)(W + 205520896);                    // 2MB
  float* pr2 = (float*)(W + 207618048);                    // 2MB
  float* pc1 = (float*)(W + 209715200);                    // 2MB
  float* pc2 = (float*)(W + 211812352);                    // 2MB
  float* F = (float*)(W + 239075328);
  float* xnf   = F;
  float* munf  = F + 16384;
  float* rinv  = F + 18432;
  float* t_r2  = F + 34816;
  float* t_dr  = F + 51200;
  float* cinv  = F + 67584;
  float* t_rs2 = F + 83968;
  float* t_sd  = F + 100352;
  float* clsh  = F + 116736;

  k_xnf<<<dim3(BB * NT / 4), 256, 0, stream>>>(x, xnf);
  k_munf<<<dim3(ESN / 64), 256, 0, stream>>>(mu, scale, munf);
  k_pack_x<<<dim3(NT / 64, DD / 64, BB), 256, 0, stream>>>(x, xnf, Xb, XT);
  k_pack_mu<<<dim3(DD / 64, ESN / 64), 256, 0, stream>>>(mu, munf, MT);
  k_logits_mfma<<<dim3(NT / 128, ESN / 128, BB), 256, 0, stream>>>(Xb, MT, E16, ET,
                                                                   pr1, pr2, pc1, pc2);
  k_rowred<<<dim3(BB * NT / 256), 256, 0, stream>>>(pr1, pr2, E16, rinv, t_r2, t_dr);
  k_colred<<<dim3(BB * ESN / 256), 256, 0, stream>>>(pc1, pc2, cinv, t_rs2, t_sd);
  k_slotin_mfma<<<dim3(ESN / 128, DD / 128, BB), 256, 0, stream>>>(ET, XT, cinv, SI);
  k_packw<<<dim3(EE * HH * DD / 4 / 256), 256, 0, stream>>>(w1, w1b, EE * HH * DD / 4);
  k_packw<<<dim3(EE * DD * HH / 4 / 256), 256, 0, stream>>>(w2, w2b, EE * DD * HH / 4);
  k_ffn1_mfma<<<dim3(SS / 128, HH / 128, BB * EE), 256, 0, stream>>>(SI, w1b, b1, H1);
  k_ffn2_mfma<<<dim3(SS / 128, DD / 128, BB * EE), 256, 0, stream>>>(H1, w2b, b2, SOT);
  k_img_mfma<<<dim3(NT / 128, DD / 128, BB), 256, 0, stream>>>(E16, SOT, rinv, out);
  k_clsA<<<dim3(BB * HH / 4), 256, 0, stream>>>(x, cls_w1, cls_b1, clsh);
  k_clsB<<<dim3(BB * DD / 4), 256, 0, stream>>>(clsh, cls_w2, cls_b2, out);
  k_metrics<<<1, 256, 0, stream>>>(t_r2, t_dr, t_rs2, t_sd, out);
}

// Round 9
// 566.149 us; speedup vs baseline: 1.2110x; 1.1644x over previous
//
#include <hip/hip_runtime.h>
#include <math.h>

// Shapes (fixed)
#define BB 8
#define SEQ 2049
#define NT 2048
#define DD 1024
#define EE 8
#define SS 256
#define ESN 2048
#define HH 512

typedef __bf16 bf16x8 __attribute__((ext_vector_type(8)));
typedef float f32x4 __attribute__((ext_vector_type(4)));

__device__ __forceinline__ float gelu_f(float v) {
  return 0.5f * v * (1.0f + erff(v * 0.70710678118654752440f));
}
__device__ __forceinline__ float wave_sum(float v) {
#pragma unroll
  for (int off = 1; off < 64; off <<= 1) v += __shfl_xor(v, off);
  return v;
}
__device__ __forceinline__ unsigned short f2bf(float f) {
  unsigned int u = __float_as_uint(f);
  u = (u + 0x7fffu + ((u >> 16) & 1u)) >> 16;
  return (unsigned short)u;
}
__device__ __forceinline__ float bf2f(unsigned short h) {
  return __uint_as_float(((unsigned int)h) << 16);
}

// async 16B/lane global->LDS stage; lbase is wave-uniform, HW adds lane*16.
__device__ __forceinline__ void stage16(const unsigned short* g, unsigned short* lbase, int lane) {
#if __has_builtin(__builtin_amdgcn_global_load_lds)
  __builtin_amdgcn_global_load_lds((const __attribute__((address_space(1))) void*)g,
                                   (__attribute__((address_space(3))) void*)lbase, 16, 0, 0);
#else
  *(int4*)(lbase + lane * 8) = *(const int4*)g;
#endif
}

// ---- bf16 gemm_bt core (round-2/5 known-good sync): C[128x128]=A[m][k]*B[n][k]^T ----
// 256 threads = 4 waves (2x2 of 64x64). LDS tiles [128][32] bf16 linear.
// Single-buffered BK=32: stage -> barrier -> compute -> barrier.
// Compute is i-blocked (bq[4] + 2 af live) to keep peak VGPR pressure low so
// __launch_bounds__(256,4) (4 blocks/CU) fits the 128-reg unified budget.
__device__ __forceinline__ void gemm_core(const unsigned short* __restrict__ A,
                                          const unsigned short* __restrict__ B,
                                          int K, unsigned short* As, unsigned short* Bs,
                                          f32x4 acc[4][4]) {
  const int t = threadIdx.x;
  const int lane = t & 63, wave = t >> 6;
  const int srow = t >> 2, scol = (t & 3) * 8;
  const int fr = lane & 15, fk = (lane >> 4) * 8;
  const int wm = (wave >> 1) * 64, wn = (wave & 1) * 64;
  const unsigned short* a0 = A + (size_t)srow * K + scol;
  const unsigned short* a1 = A + (size_t)(srow + 64) * K + scol;
  const unsigned short* b0 = B + (size_t)srow * K + scol;
  const unsigned short* b1 = B + (size_t)(srow + 64) * K + scol;
  unsigned short* lA0 = As + wave * 512;
  unsigned short* lA1 = As + 2048 + wave * 512;
  unsigned short* lB0 = Bs + wave * 512;
  unsigned short* lB1 = Bs + 2048 + wave * 512;
  for (int k0 = 0; k0 < K; k0 += 32) {
    stage16(a0 + k0, lA0, lane);
    stage16(a1 + k0, lA1, lane);
    stage16(b0 + k0, lB0, lane);
    stage16(b1 + k0, lB1, lane);
    __syncthreads();  // drains vmcnt: staged tiles visible
    bf16x8 bq[4];
#pragma unroll
    for (int j = 0; j < 4; ++j)
      bq[j] = *(const bf16x8*)(Bs + (wn + j * 16 + fr) * 32 + fk);
#pragma unroll
    for (int ib = 0; ib < 2; ++ib) {
      bf16x8 afa = *(const bf16x8*)(As + (wm + (ib * 2) * 16 + fr) * 32 + fk);
      bf16x8 afb = *(const bf16x8*)(As + (wm + (ib * 2 + 1) * 16 + fr) * 32 + fk);
#pragma unroll
      for (int j = 0; j < 4; ++j)
        acc[ib * 2][j] = __builtin_amdgcn_mfma_f32_16x16x32_bf16(afa, bq[j], acc[ib * 2][j], 0, 0, 0);
#pragma unroll
      for (int j = 0; j < 4; ++j)
        acc[ib * 2 + 1][j] = __builtin_amdgcn_mfma_f32_16x16x32_bf16(afb, bq[j], acc[ib * 2 + 1][j], 0, 0, 0);
    }
    __syncthreads();  // all reads done before next stage overwrites
  }
}

#define ACC_INIT()                                        \
  f32x4 acc[4][4];                                        \
  _Pragma("unroll") for (int i = 0; i < 4; ++i)           \
  _Pragma("unroll") for (int j = 0; j < 4; ++j)           \
  _Pragma("unroll") for (int r = 0; r < 4; ++r) acc[i][j][r] = 0.f;

#define GEMM_EPI_VARS()                                   \
  const int lane = threadIdx.x & 63, wave = threadIdx.x >> 6; \
  const int wm = (wave >> 1) * 64, wn = (wave & 1) * 64;  \
  const int fr16 = lane & 15, r4 = (lane >> 4) << 2;

// logits -> E16[n][c] direct (32B runs) + ET[c][n] via chunked LDS transpose.
__global__ __launch_bounds__(256, 4) void k_logits_mfma(const unsigned short* __restrict__ Xb,
    const unsigned short* __restrict__ MT, unsigned short* __restrict__ E16,
    unsigned short* __restrict__ ET) {
  __shared__ unsigned short LDS[8448];
  ACC_INIT();
  const int b = blockIdx.z, m0 = blockIdx.x * 128, n0 = blockIdx.y * 128;
  gemm_core(Xb + ((size_t)b * NT + m0) * DD, MT + (size_t)n0 * DD, DD, LDS, LDS + 4096, acc);
  GEMM_EPI_VARS();
  const int t = threadIdx.x;
  unsigned short* o = E16 + (size_t)b * NT * ESN;
#pragma unroll
  for (int i = 0; i < 4; ++i)
#pragma unroll
    for (int j = 0; j < 4; ++j) {
      const int gmb = m0 + wm + i * 16 + r4;
      const int gn = n0 + wn + j * 16 + fr16;
      o[(size_t)(gmb + 0) * ESN + gn] = f2bf(expf(acc[i][j][0]));
      o[(size_t)(gmb + 1) * ESN + gn] = f2bf(expf(acc[i][j][1]));
      o[(size_t)(gmb + 2) * ESN + gn] = f2bf(expf(acc[i][j][2]));
      o[(size_t)(gmb + 3) * ESN + gn] = f2bf(expf(acc[i][j][3]));
    }
  // two 64-column chunks: chunk h handled by waves with wn == h*64
#pragma unroll
  for (int h = 0; h < 2; ++h) {
    if ((wn >> 6) == h) {
#pragma unroll
      for (int i = 0; i < 4; ++i)
#pragma unroll
        for (int j = 0; j < 4; ++j) {
          ushort4 pk;
          pk.x = f2bf(expf(acc[i][j][0]));
          pk.y = f2bf(expf(acc[i][j][1]));
          pk.z = f2bf(expf(acc[i][j][2]));
          pk.w = f2bf(expf(acc[i][j][3]));
          // T[n-local][m-local], stride 132 (8B-aligned rows)
          *(ushort4*)(LDS + (j * 16 + fr16) * 132 + wm + i * 16 + r4) = pk;
        }
    }
    __syncthreads();
#pragma unroll
    for (int p = 0; p < 4; ++p) {
      const int nl = p * 16 + (t >> 4);
      const int ml = (t & 15) * 8;
      int4 v = *(const int4*)(LDS + nl * 132 + ml);
      *(int4*)(ET + ((size_t)b * ESN + n0 + h * 64 + nl) * NT + m0 + ml) = v;
    }
    __syncthreads();
  }
}

__global__ __launch_bounds__(256, 4) void k_slotin_mfma(const unsigned short* __restrict__ ET,
    const unsigned short* __restrict__ XT, const float* __restrict__ cinv,
    unsigned short* __restrict__ SI) {
  __shared__ unsigned short LDS[8192];
  ACC_INIT();
  const int b = blockIdx.z, m0 = blockIdx.x * 128, n0 = blockIdx.y * 128;
  gemm_core(ET + ((size_t)b * ESN + m0) * NT, XT + ((size_t)b * DD + n0) * NT, NT,
            LDS, LDS + 4096, acc);
  GEMM_EPI_VARS();
#pragma unroll
  for (int i = 0; i < 4; ++i)
#pragma unroll
    for (int j = 0; j < 4; ++j) {
      const int gmb = m0 + wm + i * 16 + r4;
      const int gn = n0 + wn + j * 16 + fr16;
#pragma unroll
      for (int r = 0; r < 4; ++r)
        SI[((size_t)b * ESN + gmb + r) * DD + gn] = f2bf(acc[i][j][r] * cinv[b * ESN + gmb + r]);
    }
}

__global__ __launch_bounds__(256, 4) void k_ffn1_mfma(const unsigned short* __restrict__ SI,
    const unsigned short* __restrict__ w1b, const float* __restrict__ b1,
    unsigned short* __restrict__ H1) {
  __shared__ unsigned short LDS[8192];
  ACC_INIT();
  const int z = blockIdx.z, b = z >> 3, e = z & 7;
  const int m0 = blockIdx.x * 128, n0 = blockIdx.y * 128;
  gemm_core(SI + ((size_t)b * ESN + e * SS + m0) * DD, w1b + ((size_t)e * HH + n0) * DD,
            DD, LDS, LDS + 4096, acc);
  GEMM_EPI_VARS();
#pragma unroll
  for (int i = 0; i < 4; ++i)
#pragma unroll
    for (int j = 0; j < 4; ++j) {
      const int gmb = m0 + wm + i * 16 + r4;
      const int gn = n0 + wn + j * 16 + fr16;
      const float bias = b1[e * HH + gn];
#pragma unroll
      for (int r = 0; r < 4; ++r)
        H1[((size_t)(b * EE + e) * SS + gmb + r) * HH + gn] = f2bf(gelu_f(acc[i][j][r] + bias));
    }
}

// ffn2 -> SOT[d][c] via chunked LDS transpose (coalesced 256B rows)
__global__ __launch_bounds__(256, 4) void k_ffn2_mfma(const unsigned short* __restrict__ H1,
    const unsigned short* __restrict__ w2b, const float* __restrict__ b2,
    unsigned short* __restrict__ SOT) {
  __shared__ unsigned short LDS[8448];
  ACC_INIT();
  const int z = blockIdx.z, b = z >> 3, e = z & 7;
  const int m0 = blockIdx.x * 128, n0 = blockIdx.y * 128;   // m: s within expert, n: d
  gemm_core(H1 + ((size_t)(b * EE + e) * SS + m0) * HH, w2b + ((size_t)e * DD + n0) * HH,
            HH, LDS, LDS + 4096, acc);
  GEMM_EPI_VARS();
  const int t = threadIdx.x;
#pragma unroll
  for (int h = 0; h < 2; ++h) {
    if ((wn >> 6) == h) {
#pragma unroll
      for (int i = 0; i < 4; ++i)
#pragma unroll
        for (int j = 0; j < 4; ++j) {
          const float bias = b2[e * DD + n0 + wn + j * 16 + fr16];
          ushort4 pk;
          pk.x = f2bf(acc[i][j][0] + bias);
          pk.y = f2bf(acc[i][j][1] + bias);
          pk.z = f2bf(acc[i][j][2] + bias);
          pk.w = f2bf(acc[i][j][3] + bias);
          *(ushort4*)(LDS + (j * 16 + fr16) * 132 + wm + i * 16 + r4) = pk;
        }
    }
    __syncthreads();
#pragma unroll
    for (int p = 0; p < 4; ++p) {
      const int dl = p * 16 + (t >> 4);
      const int ml = (t & 15) * 8;
      int4 v = *(const int4*)(LDS + dl * 132 + ml);
      *(int4*)(SOT + ((size_t)b * DD + n0 + h * 64 + dl) * ESN + e * SS + m0 + ml) = v;
    }
    __syncthreads();
  }
}

__global__ __launch_bounds__(256, 4) void k_img_mfma(const unsigned short* __restrict__ E16,
    const unsigned short* __restrict__ SOT, const float* __restrict__ rinv,
    float* __restrict__ out) {
  __shared__ unsigned short LDS[8192];
  ACC_INIT();
  const int b = blockIdx.z, m0 = blockIdx.x * 128, n0 = blockIdx.y * 128;
  gemm_core(E16 + ((size_t)b * NT + m0) * ESN, SOT + ((size_t)b * DD + n0) * ESN,
            ESN, LDS, LDS + 4096, acc);
  GEMM_EPI_VARS();
#pragma unroll
  for (int i = 0; i < 4; ++i)
#pragma unroll
    for (int j = 0; j < 4; ++j) {
      const int gmb = m0 + wm + i * 16 + r4;
      const int gn = n0 + wn + j * 16 + fr16;
#pragma unroll
      for (int r = 0; r < 4; ++r)
        out[((size_t)b * SEQ + 1 + gmb + r) * DD + gn] = acc[i][j][r] * rinv[b * NT + gmb + r];
    }
}

// -------- packing --------
__global__ __launch_bounds__(256) void k_xnf(const float* __restrict__ x, float* __restrict__ xnf) {
  const int wid = blockIdx.x * 4 + (threadIdx.x >> 6);
  const int lane = threadIdx.x & 63;
  const int b = wid >> 11;
  const float* row = x + ((size_t)b * SEQ + 1 + (wid & (NT - 1))) * DD;
  float s = 0.f;
#pragma unroll
  for (int k = 0; k < DD / 64; ++k) { const float v = row[lane + k * 64]; s = fmaf(v, v, s); }
  s = wave_sum(s);
  if (lane == 0) xnf[wid] = 1.0f / fmaxf(sqrtf(s), 1e-12f);
}

__global__ __launch_bounds__(256) void k_munf(const float* __restrict__ mu,
    const float* __restrict__ scale, float* __restrict__ munf) {
  __shared__ float part[4][64];
  const int c0 = blockIdx.x * 64;
  const int ci = threadIdx.x & 63, dg = threadIdx.x >> 6;
  float s = 0.f;
  for (int d = dg; d < DD; d += 4) { const float v = mu[(size_t)d * ESN + c0 + ci]; s = fmaf(v, v, s); }
  part[dg][ci] = s;
  __syncthreads();
  if (threadIdx.x < 64) {
    const float t = part[0][ci] + part[1][ci] + part[2][ci] + part[3][ci];
    munf[c0 + ci] = scale[0] / fmaxf(sqrtf(t), 1e-12f);
  }
}

__global__ __launch_bounds__(256) void k_pack_x(const float* __restrict__ x,
    const float* __restrict__ xnf, unsigned short* __restrict__ Xb,
    unsigned short* __restrict__ XT) {
  __shared__ unsigned short tile[64][72];
  const int b = blockIdx.z, n0 = blockIdx.x * 64, d0 = blockIdx.y * 64;
  const int t = threadIdx.x, tr = t >> 2, tc = (t & 3) * 16;
  const float* s = x + ((size_t)b * SEQ + 1 + n0 + tr) * DD + d0 + tc;
  const float xs = xnf[b * NT + n0 + tr];
  unsigned short tmp[16];
#pragma unroll
  for (int j = 0; j < 16; j += 4) {
    float4 v = *(const float4*)(s + j);
    tmp[j] = f2bf(v.x * xs); tmp[j + 1] = f2bf(v.y * xs);
    tmp[j + 2] = f2bf(v.z * xs); tmp[j + 3] = f2bf(v.w * xs);
  }
  *(int4*)&tile[tr][tc] = *(int4*)tmp;
  *(int4*)&tile[tr][tc + 8] = *(int4*)(tmp + 8);
  unsigned short* xb = Xb + ((size_t)b * NT + n0 + tr) * DD + d0 + tc;
  *(int4*)xb = *(int4*)tmp;
  *(int4*)(xb + 8) = *(int4*)(tmp + 8);
  __syncthreads();
  unsigned short* d = XT + ((size_t)b * DD + d0 + tr) * NT + n0 + tc;
#pragma unroll
  for (int j = 0; j < 16; ++j) tmp[j] = tile[tc + j][tr];
  *(int4*)d = *(int4*)tmp;
  *(int4*)(d + 8) = *(int4*)(tmp + 8);
}

__global__ __launch_bounds__(256) void k_pack_mu(const float* __restrict__ mu,
    const float* __restrict__ munf, unsigned short* __restrict__ MT) {
  __shared__ unsigned short tile[64][72];
  const int d0 = blockIdx.x * 64, c0 = blockIdx.y * 64;
  const int t = threadIdx.x, tr = t >> 2, tc = (t & 3) * 16;
  const float* s = mu + (size_t)(d0 + tr) * ESN + c0 + tc;
  unsigned short tmp[16];
#pragma unroll
  for (int j = 0; j < 16; j += 4) {
    float4 v = *(const float4*)(s + j);
    tmp[j] = f2bf(v.x * munf[c0 + tc + j]);
    tmp[j + 1] = f2bf(v.y * munf[c0 + tc + j + 1]);
    tmp[j + 2] = f2bf(v.z * munf[c0 + tc + j + 2]);
    tmp[j + 3] = f2bf(v.w * munf[c0 + tc + j + 3]);
  }
  *(int4*)&tile[tr][tc] = *(int4*)tmp;
  *(int4*)&tile[tr][tc + 8] = *(int4*)(tmp + 8);
  __syncthreads();
  unsigned short* d = MT + (size_t)(c0 + tr) * DD + d0 + tc;
#pragma unroll
  for (int j = 0; j < 16; ++j) tmp[j] = tile[tc + j][tr];
  *(int4*)d = *(int4*)tmp;
  *(int4*)(d + 8) = *(int4*)(tmp + 8);
}

__global__ __launch_bounds__(256) void k_packw(const float* __restrict__ w,
    unsigned short* __restrict__ o, int n4) {
  const int i = blockIdx.x * 256 + threadIdx.x;
  if (i < n4) {
    float4 v = ((const float4*)w)[i];
    ushort4 u;
    u.x = f2bf(v.x); u.y = f2bf(v.y); u.z = f2bf(v.z); u.w = f2bf(v.w);
    ((ushort4*)o)[i] = u;
  }
}

// -------- softmax stats --------
__global__ __launch_bounds__(256) void k_rowstats_e(const unsigned short* __restrict__ E,
    float* __restrict__ rinv, float* __restrict__ t_r2, float* __restrict__ t_dr) {
  const int wid = blockIdx.x * 4 + (threadIdx.x >> 6);  // b*NT + n
  const int lane = threadIdx.x & 63;
  const int n = wid & (NT - 1);
  const unsigned short* row = E + (size_t)wid * ESN;
  float s1 = 0.f, s2 = 0.f;
#pragma unroll
  for (int it = 0; it < 4; ++it) {
    int4 v = *(const int4*)(row + it * 512 + lane * 8);
    const unsigned short* u = (const unsigned short*)&v;
#pragma unroll
    for (int j = 0; j < 8; ++j) { const float e = bf2f(u[j]); s1 += e; s2 = fmaf(e, e, s2); }
  }
  s1 = wave_sum(s1); s2 = wave_sum(s2);
  if (lane == 0) {
    const float ri = 1.0f / s1;
    rinv[wid] = ri;
    const float r2 = 1.0f / (s2 * ri * ri + 1e-9f);
    t_r2[wid] = r2;
    t_dr[wid] = bf2f(row[n]) * ri * r2;
  }
}

__global__ __launch_bounds__(256) void k_colstats(const unsigned short* __restrict__ ET,
    float* __restrict__ cinv, float* __restrict__ t_rs2, float* __restrict__ t_sd) {
  const int wid = blockIdx.x * 4 + (threadIdx.x >> 6);  // b*ESN + c
  const int lane = threadIdx.x & 63;
  const unsigned short* row = ET + (size_t)wid * NT;
  float s1 = 0.f, s2 = 0.f;
#pragma unroll
  for (int it = 0; it < 4; ++it) {
    int4 v = *(const int4*)(row + it * 512 + lane * 8);
    const unsigned short* u = (const unsigned short*)&v;
#pragma unroll
    for (int j = 0; j < 8; ++j) { const float e = bf2f(u[j]); s1 += e; s2 = fmaf(e, e, s2); }
  }
  s1 = wave_sum(s1); s2 = wave_sum(s2);
  if (lane == 0) {
    const float ci = 1.0f / s1;
    cinv[wid] = ci;
    const float rs2 = 1.0f / (s2 * ci * ci + 1e-9f);
    t_rs2[wid] = rs2;
    const int c = wid & (ESN - 1);
    t_sd[wid] = ((c % 257) == 0) ? rs2 : 0.f;
  }
}

// -------- cls path --------
__global__ __launch_bounds__(256) void k_clsA(const float* __restrict__ x,
    const float* __restrict__ w1, const float* __restrict__ b1, float* __restrict__ clsh) {
  const int wid = blockIdx.x * 4 + (threadIdx.x >> 6);
  const int lane = threadIdx.x & 63;
  const int b = wid >> 9, h = wid & (HH - 1);
  const float* xr = x + (size_t)b * SEQ * DD;
  const float* wr = w1 + (size_t)h * DD;
  float s = 0.f;
#pragma unroll
  for (int k = 0; k < DD / 64; ++k) s = fmaf(xr[lane + k * 64], wr[lane + k * 64], s);
  s = wave_sum(s);
  if (lane == 0) clsh[wid] = gelu_f(s + b1[h]);
}

__global__ __launch_bounds__(256) void k_clsB(const float* __restrict__ clsh,
    const float* __restrict__ w2, const float* __restrict__ b2, float* __restrict__ out) {
  const int wid = blockIdx.x * 4 + (threadIdx.x >> 6);
  const int lane = threadIdx.x & 63;
  const int b = wid >> 10, d = wid & (DD - 1);
  const float* hr = clsh + (size_t)b * HH;
  const float* wr = w2 + (size_t)d * HH;
  float s = 0.f;
#pragma unroll
  for (int k = 0; k < HH / 64; ++k) s = fmaf(hr[lane + k * 64], wr[lane + k * 64], s);
  s = wave_sum(s);
  if (lane == 0) out[(size_t)b * SEQ * DD + d] = s + b2[d];
}

__global__ __launch_bounds__(256) void k_metrics(const float* __restrict__ t_r2,
    const float* __restrict__ t_dr, const float* __restrict__ t_rs2,
    const float* __restrict__ t_sd, float* __restrict__ out) {
  __shared__ float sm[256];
  const int tid = threadIdx.x;
  float a = 0.f, b = 0.f, c = 0.f, d = 0.f;
  for (int i = tid; i < BB * NT; i += 256) { a += t_r2[i]; b += t_dr[i]; }
  for (int i = tid; i < BB * ESN; i += 256) { c += t_rs2[i]; d += t_sd[i]; }
  float vals[4] = {a, b, c, d};
  float res[4];
#pragma unroll
  for (int v = 0; v < 4; ++v) {
    sm[tid] = vals[v];
    __syncthreads();
    for (int s = 128; s > 0; s >>= 1) {
      if (tid < s) sm[tid] += sm[tid + s];
      __syncthreads();
    }
    res[v] = sm[0];
    __syncthreads();
  }
  if (tid == 0) {
    out[(size_t)BB * SEQ * DD] = (res[0] - res[1]) / 33538048.0f;
    out[(size_t)BB * SEQ * DD + 1] = (res[2] - res[3]) / 33538048.0f;
  }
}

extern "C" void kernel_launch(void* const* d_in, const int* in_sizes, int n_in,
                              void* d_out, int out_size, void* d_ws, size_t ws_size,
                              hipStream_t stream) {
  const float* x      = (const float*)d_in[0];
  const float* mu     = (const float*)d_in[1];
  const float* scale  = (const float*)d_in[2];
  const float* cls_w1 = (const float*)d_in[3];
  const float* cls_b1 = (const float*)d_in[4];
  const float* cls_w2 = (const float*)d_in[5];
  const float* cls_b2 = (const float*)d_in[6];
  const float* w1     = (const float*)d_in[7];
  const float* b1     = (const float*)d_in[8];
  const float* w2     = (const float*)d_in[9];
  const float* b2     = (const float*)d_in[10];
  float* out = (float*)d_out;

  // workspace plan (bytes), aliasing by lifetime:
  char* W = (char*)d_ws;
  unsigned short* XT  = (unsigned short*)(W);              // 32MB; H1 aliases after slotin
  unsigned short* Xb  = (unsigned short*)(W + 33554432);   // 32MB; SOT aliases after logits
  unsigned short* MT  = (unsigned short*)(W + 67108864);   //  4MB
  unsigned short* E16 = (unsigned short*)(W + 71303168);   // 64MB (lives until img)
  unsigned short* ET  = (unsigned short*)(W + 138412032);  // 64MB; w1b/w2b alias after slotin
  unsigned short* SI  = (unsigned short*)(W + 205520896);  // 32MB
  unsigned short* H1  = (unsigned short*)(W);              // 16MB (alias XT)
  unsigned short* SOT = (unsigned short*)(W + 33554432);   // 32MB (alias Xb)
  unsigned short* w1b = (unsigned short*)(W + 138412032);  //  8MB (alias ET)
  unsigned short* w2b = (unsigned short*)(W + 146800640);  //  8MB (alias ET)
  float* F = (float*)(W + 239075328);
  float* xnf   = F;
  float* munf  = F + 16384;
  float* rinv  = F + 18432;
  float* t_r2  = F + 34816;
  float* t_dr  = F + 51200;
  float* cinv  = F + 67584;
  float* t_rs2 = F + 83968;
  float* t_sd  = F + 100352;
  float* clsh  = F + 116736;

  k_xnf<<<dim3(BB * NT / 4), 256, 0, stream>>>(x, xnf);
  k_munf<<<dim3(ESN / 64), 256, 0, stream>>>(mu, scale, munf);
  k_pack_x<<<dim3(NT / 64, DD / 64, BB), 256, 0, stream>>>(x, xnf, Xb, XT);
  k_pack_mu<<<dim3(DD / 64, ESN / 64), 256, 0, stream>>>(mu, munf, MT);
  k_logits_mfma<<<dim3(NT / 128, ESN / 128, BB), 256, 0, stream>>>(Xb, MT, E16, ET);
  k_rowstats_e<<<dim3(BB * NT / 4), 256, 0, stream>>>(E16, rinv, t_r2, t_dr);
  k_colstats<<<dim3(BB * ESN / 4), 256, 0, stream>>>(ET, cinv, t_rs2, t_sd);
  k_slotin_mfma<<<dim3(ESN / 128, DD / 128, BB), 256, 0, stream>>>(ET, XT, cinv, SI);
  k_packw<<<dim3(EE * HH * DD / 4 / 256), 256, 0, stream>>>(w1, w1b, EE * HH * DD / 4);
  k_packw<<<dim3(EE * DD * HH / 4 / 256), 256, 0, stream>>>(w2, w2b, EE * DD * HH / 4);
  k_ffn1_mfma<<<dim3(SS / 128, HH / 128, BB * EE), 256, 0, stream>>>(SI, w1b, b1, H1);
  k_ffn2_mfma<<<dim3(SS / 128, DD / 128, BB * EE), 256, 0, stream>>>(H1, w2b, b2, SOT);
  k_img_mfma<<<dim3(NT / 128, DD / 128, BB), 256, 0, stream>>>(E16, SOT, rinv, out);
  k_clsA<<<dim3(BB * HH / 4), 256, 0, stream>>>(x, cls_w1, cls_b1, clsh);
  k_clsB<<<dim3(BB * DD / 4), 256, 0, stream>>>(clsh, cls_w2, cls_b2, out);
  k_metrics<<<1, 256, 0, stream>>>(t_r2, t_dr, t_rs2, t_sd, out);
}

// Round 10
// 464.049 us; speedup vs baseline: 1.4775x; 1.2200x over previous
//
#include <hip/hip_runtime.h>
#include <math.h>

// Shapes (fixed)
#define BB 8
#define SEQ 2049
#define NT 2048
#define DD 1024
#define EE 8
#define SS 256
#define ESN 2048
#define HH 512

typedef __bf16 bf16x8 __attribute__((ext_vector_type(8)));
typedef float f32x4 __attribute__((ext_vector_type(4)));

__device__ __forceinline__ float gelu_f(float v) {
  return 0.5f * v * (1.0f + erff(v * 0.70710678118654752440f));
}
__device__ __forceinline__ float wave_sum(float v) {
#pragma unroll
  for (int off = 1; off < 64; off <<= 1) v += __shfl_xor(v, off);
  return v;
}
__device__ __forceinline__ unsigned short f2bf(float f) {
  unsigned int u = __float_as_uint(f);
  u = (u + 0x7fffu + ((u >> 16) & 1u)) >> 16;
  return (unsigned short)u;
}
__device__ __forceinline__ float bf2f(unsigned short h) {
  return __uint_as_float(((unsigned int)h) << 16);
}

// async 16B/lane global->LDS stage; lbase is wave-uniform, HW adds lane*16.
__device__ __forceinline__ void stage16(const unsigned short* g, unsigned short* lbase, int lane) {
#if __has_builtin(__builtin_amdgcn_global_load_lds)
  __builtin_amdgcn_global_load_lds((const __attribute__((address_space(1))) void*)g,
                                   (__attribute__((address_space(3))) void*)lbase, 16, 0, 0);
#else
  *(int4*)(lbase + lane * 8) = *(const int4*)g;
#endif
}

// ---- bf16 gemm_bt core (round-2/5 known-good sync): C[128x128]=A[m][k]*B[n][k]^T ----
// 256 threads = 4 waves (2x2 of 64x64). LDS tiles [128][32] bf16 linear.
// Single-buffered BK=32: stage -> barrier -> compute -> barrier.
// Compute is i-blocked (bq[4] + 2 af live) so __launch_bounds__(256,4) fits 128 regs.
__device__ __forceinline__ void gemm_core(const unsigned short* __restrict__ A,
                                          const unsigned short* __restrict__ B,
                                          int K, unsigned short* As, unsigned short* Bs,
                                          f32x4 acc[4][4]) {
  const int t = threadIdx.x;
  const int lane = t & 63, wave = t >> 6;
  const int srow = t >> 2, scol = (t & 3) * 8;
  const int fr = lane & 15, fk = (lane >> 4) * 8;
  const int wm = (wave >> 1) * 64, wn = (wave & 1) * 64;
  const unsigned short* a0 = A + (size_t)srow * K + scol;
  const unsigned short* a1 = A + (size_t)(srow + 64) * K + scol;
  const unsigned short* b0 = B + (size_t)srow * K + scol;
  const unsigned short* b1 = B + (size_t)(srow + 64) * K + scol;
  unsigned short* lA0 = As + wave * 512;
  unsigned short* lA1 = As + 2048 + wave * 512;
  unsigned short* lB0 = Bs + wave * 512;
  unsigned short* lB1 = Bs + 2048 + wave * 512;
  for (int k0 = 0; k0 < K; k0 += 32) {
    stage16(a0 + k0, lA0, lane);
    stage16(a1 + k0, lA1, lane);
    stage16(b0 + k0, lB0, lane);
    stage16(b1 + k0, lB1, lane);
    __syncthreads();  // drains vmcnt: staged tiles visible
    bf16x8 bq[4];
#pragma unroll
    for (int j = 0; j < 4; ++j)
      bq[j] = *(const bf16x8*)(Bs + (wn + j * 16 + fr) * 32 + fk);
#pragma unroll
    for (int ib = 0; ib < 2; ++ib) {
      bf16x8 afa = *(const bf16x8*)(As + (wm + (ib * 2) * 16 + fr) * 32 + fk);
      bf16x8 afb = *(const bf16x8*)(As + (wm + (ib * 2 + 1) * 16 + fr) * 32 + fk);
#pragma unroll
      for (int j = 0; j < 4; ++j)
        acc[ib * 2][j] = __builtin_amdgcn_mfma_f32_16x16x32_bf16(afa, bq[j], acc[ib * 2][j], 0, 0, 0);
#pragma unroll
      for (int j = 0; j < 4; ++j)
        acc[ib * 2 + 1][j] = __builtin_amdgcn_mfma_f32_16x16x32_bf16(afb, bq[j], acc[ib * 2 + 1][j], 0, 0, 0);
    }
    __syncthreads();  // all reads done before next stage overwrites
  }
}

#define ACC_INIT()                                        \
  f32x4 acc[4][4];                                        \
  _Pragma("unroll") for (int i = 0; i < 4; ++i)           \
  _Pragma("unroll") for (int j = 0; j < 4; ++j)           \
  _Pragma("unroll") for (int r = 0; r < 4; ++r) acc[i][j][r] = 0.f;

#define GEMM_EPI_VARS()                                   \
  const int lane = threadIdx.x & 63, wave = threadIdx.x >> 6; \
  const int wm = (wave >> 1) * 64, wn = (wave & 1) * 64;  \
  const int fr16 = lane & 15, r4 = (lane >> 4) << 2;

// logits -> E16[n][c] direct (32B runs) + ET[c][n] via chunked LDS transpose.
__global__ __launch_bounds__(256, 4) void k_logits_mfma(const unsigned short* __restrict__ Xb,
    const unsigned short* __restrict__ MT, unsigned short* __restrict__ E16,
    unsigned short* __restrict__ ET) {
  __shared__ unsigned short LDS[8448];
  ACC_INIT();
  const int b = blockIdx.z, m0 = blockIdx.x * 128, n0 = blockIdx.y * 128;
  gemm_core(Xb + ((size_t)b * NT + m0) * DD, MT + (size_t)n0 * DD, DD, LDS, LDS + 4096, acc);
  GEMM_EPI_VARS();
  const int t = threadIdx.x;
  unsigned short* o = E16 + (size_t)b * NT * ESN;
#pragma unroll
  for (int i = 0; i < 4; ++i)
#pragma unroll
    for (int j = 0; j < 4; ++j) {
      const int gmb = m0 + wm + i * 16 + r4;
      const int gn = n0 + wn + j * 16 + fr16;
      o[(size_t)(gmb + 0) * ESN + gn] = f2bf(expf(acc[i][j][0]));
      o[(size_t)(gmb + 1) * ESN + gn] = f2bf(expf(acc[i][j][1]));
      o[(size_t)(gmb + 2) * ESN + gn] = f2bf(expf(acc[i][j][2]));
      o[(size_t)(gmb + 3) * ESN + gn] = f2bf(expf(acc[i][j][3]));
    }
  // two 64-column chunks: chunk h handled by waves with wn == h*64
#pragma unroll
  for (int h = 0; h < 2; ++h) {
    if ((wn >> 6) == h) {
#pragma unroll
      for (int i = 0; i < 4; ++i)
#pragma unroll
        for (int j = 0; j < 4; ++j) {
          ushort4 pk;
          pk.x = f2bf(expf(acc[i][j][0]));
          pk.y = f2bf(expf(acc[i][j][1]));
          pk.z = f2bf(expf(acc[i][j][2]));
          pk.w = f2bf(expf(acc[i][j][3]));
          // T[n-local][m-local], stride 132 (8B-aligned rows)
          *(ushort4*)(LDS + (j * 16 + fr16) * 132 + wm + i * 16 + r4) = pk;
        }
    }
    __syncthreads();
#pragma unroll
    for (int p = 0; p < 4; ++p) {
      const int nl = p * 16 + (t >> 4);
      const int ml = (t & 15) * 8;
      int4 v = *(const int4*)(LDS + nl * 132 + ml);
      *(int4*)(ET + ((size_t)b * ESN + n0 + h * 64 + nl) * NT + m0 + ml) = v;
    }
    __syncthreads();
  }
}

__global__ __launch_bounds__(256, 4) void k_slotin_mfma(const unsigned short* __restrict__ ET,
    const unsigned short* __restrict__ XT, const float* __restrict__ cinv,
    unsigned short* __restrict__ SI) {
  __shared__ unsigned short LDS[8192];
  ACC_INIT();
  const int b = blockIdx.z, m0 = blockIdx.x * 128, n0 = blockIdx.y * 128;
  gemm_core(ET + ((size_t)b * ESN + m0) * NT, XT + ((size_t)b * DD + n0) * NT, NT,
            LDS, LDS + 4096, acc);
  GEMM_EPI_VARS();
#pragma unroll
  for (int i = 0; i < 4; ++i)
#pragma unroll
    for (int j = 0; j < 4; ++j) {
      const int gmb = m0 + wm + i * 16 + r4;
      const int gn = n0 + wn + j * 16 + fr16;
#pragma unroll
      for (int r = 0; r < 4; ++r)
        SI[((size_t)b * ESN + gmb + r) * DD + gn] = f2bf(acc[i][j][r] * cinv[b * ESN + gmb + r]);
    }
}

__global__ __launch_bounds__(256, 4) void k_ffn1_mfma(const unsigned short* __restrict__ SI,
    const unsigned short* __restrict__ w1b, const float* __restrict__ b1,
    unsigned short* __restrict__ H1) {
  __shared__ unsigned short LDS[8192];
  ACC_INIT();
  const int z = blockIdx.z, b = z >> 3, e = z & 7;
  const int m0 = blockIdx.x * 128, n0 = blockIdx.y * 128;
  gemm_core(SI + ((size_t)b * ESN + e * SS + m0) * DD, w1b + ((size_t)e * HH + n0) * DD,
            DD, LDS, LDS + 4096, acc);
  GEMM_EPI_VARS();
#pragma unroll
  for (int i = 0; i < 4; ++i)
#pragma unroll
    for (int j = 0; j < 4; ++j) {
      const int gmb = m0 + wm + i * 16 + r4;
      const int gn = n0 + wn + j * 16 + fr16;
      const float bias = b1[e * HH + gn];
#pragma unroll
      for (int r = 0; r < 4; ++r)
        H1[((size_t)(b * EE + e) * SS + gmb + r) * HH + gn] = f2bf(gelu_f(acc[i][j][r] + bias));
    }
}

// ffn2 -> SOT[d][c] via chunked LDS transpose (coalesced 256B rows)
__global__ __launch_bounds__(256, 4) void k_ffn2_mfma(const unsigned short* __restrict__ H1,
    const unsigned short* __restrict__ w2b, const float* __restrict__ b2,
    unsigned short* __restrict__ SOT) {
  __shared__ unsigned short LDS[8448];
  ACC_INIT();
  const int z = blockIdx.z, b = z >> 3, e = z & 7;
  const int m0 = blockIdx.x * 128, n0 = blockIdx.y * 128;   // m: s within expert, n: d
  gemm_core(H1 + ((size_t)(b * EE + e) * SS + m0) * HH, w2b + ((size_t)e * DD + n0) * HH,
            HH, LDS, LDS + 4096, acc);
  GEMM_EPI_VARS();
  const int t = threadIdx.x;
#pragma unroll
  for (int h = 0; h < 2; ++h) {
    if ((wn >> 6) == h) {
#pragma unroll
      for (int i = 0; i < 4; ++i)
#pragma unroll
        for (int j = 0; j < 4; ++j) {
          const float bias = b2[e * DD + n0 + wn + j * 16 + fr16];
          ushort4 pk;
          pk.x = f2bf(acc[i][j][0] + bias);
          pk.y = f2bf(acc[i][j][1] + bias);
          pk.z = f2bf(acc[i][j][2] + bias);
          pk.w = f2bf(acc[i][j][3] + bias);
          *(ushort4*)(LDS + (j * 16 + fr16) * 132 + wm + i * 16 + r4) = pk;
        }
    }
    __syncthreads();
#pragma unroll
    for (int p = 0; p < 4; ++p) {
      const int dl = p * 16 + (t >> 4);
      const int ml = (t & 15) * 8;
      int4 v = *(const int4*)(LDS + dl * 132 + ml);
      *(int4*)(SOT + ((size_t)b * DD + n0 + h * 64 + dl) * ESN + e * SS + m0 + ml) = v;
    }
    __syncthreads();
  }
}

__global__ __launch_bounds__(256, 4) void k_img_mfma(const unsigned short* __restrict__ E16,
    const unsigned short* __restrict__ SOT, const float* __restrict__ rinv,
    float* __restrict__ out) {
  __shared__ unsigned short LDS[8192];
  ACC_INIT();
  const int b = blockIdx.z, m0 = blockIdx.x * 128, n0 = blockIdx.y * 128;
  gemm_core(E16 + ((size_t)b * NT + m0) * ESN, SOT + ((size_t)b * DD + n0) * ESN,
            ESN, LDS, LDS + 4096, acc);
  GEMM_EPI_VARS();
#pragma unroll
  for (int i = 0; i < 4; ++i)
#pragma unroll
    for (int j = 0; j < 4; ++j) {
      const int gmb = m0 + wm + i * 16 + r4;
      const int gn = n0 + wn + j * 16 + fr16;
#pragma unroll
      for (int r = 0; r < 4; ++r)
        out[((size_t)b * SEQ + 1 + gmb + r) * DD + gn] = acc[i][j][r] * rinv[b * NT + gmb + r];
    }
}

// -------- packing --------
__global__ __launch_bounds__(256) void k_xnf(const float* __restrict__ x, float* __restrict__ xnf) {
  const int wid = blockIdx.x * 4 + (threadIdx.x >> 6);
  const int lane = threadIdx.x & 63;
  const int b = wid >> 11;
  const float* row = x + ((size_t)b * SEQ + 1 + (wid & (NT - 1))) * DD;
  float s = 0.f;
#pragma unroll
  for (int k = 0; k < DD / 64; ++k) { const float v = row[lane + k * 64]; s = fmaf(v, v, s); }
  s = wave_sum(s);
  if (lane == 0) xnf[wid] = 1.0f / fmaxf(sqrtf(s), 1e-12f);
}

// mu column-norm, 2-stage (round-9 k_munf was 114us at 1.4% occupancy):
// part: grid(ESN/256, 16) — block sums 64 d-rows for 256 contiguous cols.
__global__ __launch_bounds__(256) void k_munf_part(const float* __restrict__ mu,
    float* __restrict__ pm) {
  const int c = blockIdx.x * 256 + threadIdx.x;
  const int d0 = blockIdx.y * (DD / 16);
  float s = 0.f;
  for (int d = d0; d < d0 + DD / 16; ++d) {
    const float v = mu[(size_t)d * ESN + c];
    s = fmaf(v, v, s);
  }
  pm[blockIdx.y * ESN + c] = s;
}

__global__ __launch_bounds__(256) void k_munf_red(const float* __restrict__ pm,
    const float* __restrict__ scale, float* __restrict__ munf) {
  const int c = blockIdx.x * 256 + threadIdx.x;
  float s = 0.f;
#pragma unroll
  for (int k = 0; k < 16; ++k) s += pm[k * ESN + c];
  munf[c] = scale[0] / fmaxf(sqrtf(s), 1e-12f);
}

__global__ __launch_bounds__(256) void k_pack_x(const float* __restrict__ x,
    const float* __restrict__ xnf, unsigned short* __restrict__ Xb,
    unsigned short* __restrict__ XT) {
  __shared__ unsigned short tile[64][72];
  const int b = blockIdx.z, n0 = blockIdx.x * 64, d0 = blockIdx.y * 64;
  const int t = threadIdx.x, tr = t >> 2, tc = (t & 3) * 16;
  const float* s = x + ((size_t)b * SEQ + 1 + n0 + tr) * DD + d0 + tc;
  const float xs = xnf[b * NT + n0 + tr];
  unsigned short tmp[16];
#pragma unroll
  for (int j = 0; j < 16; j += 4) {
    float4 v = *(const float4*)(s + j);
    tmp[j] = f2bf(v.x * xs); tmp[j + 1] = f2bf(v.y * xs);
    tmp[j + 2] = f2bf(v.z * xs); tmp[j + 3] = f2bf(v.w * xs);
  }
  *(int4*)&tile[tr][tc] = *(int4*)tmp;
  *(int4*)&tile[tr][tc + 8] = *(int4*)(tmp + 8);
  unsigned short* xb = Xb + ((size_t)b * NT + n0 + tr) * DD + d0 + tc;
  *(int4*)xb = *(int4*)tmp;
  *(int4*)(xb + 8) = *(int4*)(tmp + 8);
  __syncthreads();
  unsigned short* d = XT + ((size_t)b * DD + d0 + tr) * NT + n0 + tc;
#pragma unroll
  for (int j = 0; j < 16; ++j) tmp[j] = tile[tc + j][tr];
  *(int4*)d = *(int4*)tmp;
  *(int4*)(d + 8) = *(int4*)(tmp + 8);
}

__global__ __launch_bounds__(256) void k_pack_mu(const float* __restrict__ mu,
    const float* __restrict__ munf, unsigned short* __restrict__ MT) {
  __shared__ unsigned short tile[64][72];
  const int d0 = blockIdx.x * 64, c0 = blockIdx.y * 64;
  const int t = threadIdx.x, tr = t >> 2, tc = (t & 3) * 16;
  const float* s = mu + (size_t)(d0 + tr) * ESN + c0 + tc;
  unsigned short tmp[16];
#pragma unroll
  for (int j = 0; j < 16; j += 4) {
    float4 v = *(const float4*)(s + j);
    tmp[j] = f2bf(v.x * munf[c0 + tc + j]);
    tmp[j + 1] = f2bf(v.y * munf[c0 + tc + j + 1]);
    tmp[j + 2] = f2bf(v.z * munf[c0 + tc + j + 2]);
    tmp[j + 3] = f2bf(v.w * munf[c0 + tc + j + 3]);
  }
  *(int4*)&tile[tr][tc] = *(int4*)tmp;
  *(int4*)&tile[tr][tc + 8] = *(int4*)(tmp + 8);
  __syncthreads();
  unsigned short* d = MT + (size_t)(c0 + tr) * DD + d0 + tc;
#pragma unroll
  for (int j = 0; j < 16; ++j) tmp[j] = tile[tc + j][tr];
  *(int4*)d = *(int4*)tmp;
  *(int4*)(d + 8) = *(int4*)(tmp + 8);
}

__global__ __launch_bounds__(256) void k_packw(const float* __restrict__ w,
    unsigned short* __restrict__ o, int n4) {
  const int i = blockIdx.x * 256 + threadIdx.x;
  if (i < n4) {
    float4 v = ((const float4*)w)[i];
    ushort4 u;
    u.x = f2bf(v.x); u.y = f2bf(v.y); u.z = f2bf(v.z); u.w = f2bf(v.w);
    ((ushort4*)o)[i] = u;
  }
}

// -------- softmax stats --------
__global__ __launch_bounds__(256) void k_rowstats_e(const unsigned short* __restrict__ E,
    float* __restrict__ rinv, float* __restrict__ t_r2, float* __restrict__ t_dr) {
  const int wid = blockIdx.x * 4 + (threadIdx.x >> 6);  // b*NT + n
  const int lane = threadIdx.x & 63;
  const int n = wid & (NT - 1);
  const unsigned short* row = E + (size_t)wid * ESN;
  float s1 = 0.f, s2 = 0.f;
#pragma unroll
  for (int it = 0; it < 4; ++it) {
    int4 v = *(const int4*)(row + it * 512 + lane * 8);
    const unsigned short* u = (const unsigned short*)&v;
#pragma unroll
    for (int j = 0; j < 8; ++j) { const float e = bf2f(u[j]); s1 += e; s2 = fmaf(e, e, s2); }
  }
  s1 = wave_sum(s1); s2 = wave_sum(s2);
  if (lane == 0) {
    const float ri = 1.0f / s1;
    rinv[wid] = ri;
    const float r2 = 1.0f / (s2 * ri * ri + 1e-9f);
    t_r2[wid] = r2;
    t_dr[wid] = bf2f(row[n]) * ri * r2;
  }
}

__global__ __launch_bounds__(256) void k_colstats(const unsigned short* __restrict__ ET,
    float* __restrict__ cinv, float* __restrict__ t_rs2, float* __restrict__ t_sd) {
  const int wid = blockIdx.x * 4 + (threadIdx.x >> 6);  // b*ESN + c
  const int lane = threadIdx.x & 63;
  const unsigned short* row = ET + (size_t)wid * NT;
  float s1 = 0.f, s2 = 0.f;
#pragma unroll
  for (int it = 0; it < 4; ++it) {
    int4 v = *(const int4*)(row + it * 512 + lane * 8);
    const unsigned short* u = (const unsigned short*)&v;
#pragma unroll
    for (int j = 0; j < 8; ++j) { const float e = bf2f(u[j]); s1 += e; s2 = fmaf(e, e, s2); }
  }
  s1 = wave_sum(s1); s2 = wave_sum(s2);
  if (lane == 0) {
    const float ci = 1.0f / s1;
    cinv[wid] = ci;
    const float rs2 = 1.0f / (s2 * ci * ci + 1e-9f);
    t_rs2[wid] = rs2;
    const int c = wid & (ESN - 1);
    t_sd[wid] = ((c % 257) == 0) ? rs2 : 0.f;
  }
}

// -------- cls path --------
__global__ __launch_bounds__(256) void k_clsA(const float* __restrict__ x,
    const float* __restrict__ w1, const float* __restrict__ b1, float* __restrict__ clsh) {
  const int wid = blockIdx.x * 4 + (threadIdx.x >> 6);
  const int lane = threadIdx.x & 63;
  const int b = wid >> 9, h = wid & (HH - 1);
  const float* xr = x + (size_t)b * SEQ * DD;
  const float* wr = w1 + (size_t)h * DD;
  float s = 0.f;
#pragma unroll
  for (int k = 0; k < DD / 64; ++k) s = fmaf(xr[lane + k * 64], wr[lane + k * 64], s);
  s = wave_sum(s);
  if (lane == 0) clsh[wid] = gelu_f(s + b1[h]);
}

__global__ __launch_bounds__(256) void k_clsB(const float* __restrict__ clsh,
    const float* __restrict__ w2, const float* __restrict__ b2, float* __restrict__ out) {
  const int wid = blockIdx.x * 4 + (threadIdx.x >> 6);
  const int lane = threadIdx.x & 63;
  const int b = wid >> 10, d = wid & (DD - 1);
  const float* hr = clsh + (size_t)b * HH;
  const float* wr = w2 + (size_t)d * HH;
  float s = 0.f;
#pragma unroll
  for (int k = 0; k < HH / 64; ++k) s = fmaf(hr[lane + k * 64], wr[lane + k * 64], s);
  s = wave_sum(s);
  if (lane == 0) out[(size_t)b * SEQ * DD + d] = s + b2[d];
}

__global__ __launch_bounds__(256) void k_metrics(const float* __restrict__ t_r2,
    const float* __restrict__ t_dr, const float* __restrict__ t_rs2,
    const float* __restrict__ t_sd, float* __restrict__ out) {
  __shared__ float sm[256];
  const int tid = threadIdx.x;
  float a = 0.f, b = 0.f, c = 0.f, d = 0.f;
  for (int i = tid; i < BB * NT; i += 256) { a += t_r2[i]; b += t_dr[i]; }
  for (int i = tid; i < BB * ESN; i += 256) { c += t_rs2[i]; d += t_sd[i]; }
  float vals[4] = {a, b, c, d};
  float res[4];
#pragma unroll
  for (int v = 0; v < 4; ++v) {
    sm[tid] = vals[v];
    __syncthreads();
    for (int s = 128; s > 0; s >>= 1) {
      if (tid < s) sm[tid] += sm[tid + s];
      __syncthreads();
    }
    res[v] = sm[0];
    __syncthreads();
  }
  if (tid == 0) {
    out[(size_t)BB * SEQ * DD] = (res[0] - res[1]) / 33538048.0f;
    out[(size_t)BB * SEQ * DD + 1] = (res[2] - res[3]) / 33538048.0f;
  }
}

extern "C" void kernel_launch(void* const* d_in, const int* in_sizes, int n_in,
                              void* d_out, int out_size, void* d_ws, size_t ws_size,
                              hipStream_t stream) {
  const float* x      = (const float*)d_in[0];
  const float* mu     = (const float*)d_in[1];
  const float* scale  = (const float*)d_in[2];
  const float* cls_w1 = (const float*)d_in[3];
  const float* cls_b1 = (const float*)d_in[4];
  const float* cls_w2 = (const float*)d_in[5];
  const float* cls_b2 = (const float*)d_in[6];
  const float* w1     = (const float*)d_in[7];
  const float* b1     = (const float*)d_in[8];
  const float* w2     = (const float*)d_in[9];
  const float* b2     = (const float*)d_in[10];
  float* out = (float*)d_out;

  // workspace plan (bytes), aliasing by lifetime:
  char* W = (char*)d_ws;
  unsigned short* XT  = (unsigned short*)(W);              // 32MB; H1 aliases after slotin
  unsigned short* Xb  = (unsigned short*)(W + 33554432);   // 32MB; SOT aliases after logits
  unsigned short* MT  = (unsigned short*)(W + 67108864);   //  4MB
  unsigned short* E16 = (unsigned short*)(W + 71303168);   // 64MB (written by logits; munf partials alias before that)
  unsigned short* ET  = (unsigned short*)(W + 138412032);  // 64MB; w1b/w2b alias after slotin
  unsigned short* SI  = (unsigned short*)(W + 205520896);  // 32MB
  unsigned short* H1  = (unsigned short*)(W);              // 16MB (alias XT)
  unsigned short* SOT = (unsigned short*)(W + 33554432);   // 32MB (alias Xb)
  unsigned short* w1b = (unsigned short*)(W + 138412032);  //  8MB (alias ET)
  unsigned short* w2b = (unsigned short*)(W + 146800640);  //  8MB (alias ET)
  float* pmunf = (float*)(W + 71303168);                   // 128KB (alias E16, dead before logits)
  float* F = (float*)(W + 239075328);
  float* xnf   = F;
  float* munf  = F + 16384;
  float* rinv  = F + 18432;
  float* t_r2  = F + 34816;
  float* t_dr  = F + 51200;
  float* cinv  = F + 67584;
  float* t_rs2 = F + 83968;
  float* t_sd  = F + 100352;
  float* clsh  = F + 116736;

  k_xnf<<<dim3(BB * NT / 4), 256, 0, stream>>>(x, xnf);
  k_munf_part<<<dim3(ESN / 256, 16), 256, 0, stream>>>(mu, pmunf);
  k_munf_red<<<dim3(ESN / 256), 256, 0, stream>>>(pmunf, scale, munf);
  k_pack_x<<<dim3(NT / 64, DD / 64, BB), 256, 0, stream>>>(x, xnf, Xb, XT);
  k_pack_mu<<<dim3(DD / 64, ESN / 64), 256, 0, stream>>>(mu, munf, MT);
  k_logits_mfma<<<dim3(NT / 128, ESN / 128, BB), 256, 0, stream>>>(Xb, MT, E16, ET);
  k_rowstats_e<<<dim3(BB * NT / 4), 256, 0, stream>>>(E16, rinv, t_r2, t_dr);
  k_colstats<<<dim3(BB * ESN / 4), 256, 0, stream>>>(ET, cinv, t_rs2, t_sd);
  k_slotin_mfma<<<dim3(ESN / 128, DD / 128, BB), 256, 0, stream>>>(ET, XT, cinv, SI);
  k_packw<<<dim3(EE * HH * DD / 4 / 256), 256, 0, stream>>>(w1, w1b, EE * HH * DD / 4);
  k_packw<<<dim3(EE * DD * HH / 4 / 256), 256, 0, stream>>>(w2, w2b, EE * DD * HH / 4);
  k_ffn1_mfma<<<dim3(SS / 128, HH / 128, BB * EE), 256, 0, stream>>>(SI, w1b, b1, H1);
  k_ffn2_mfma<<<dim3(SS / 128, DD / 128, BB * EE), 256, 0, stream>>>(H1, w2b, b2, SOT);
  k_img_mfma<<<dim3(NT / 128, DD / 128, BB), 256, 0, stream>>>(E16, SOT, rinv, out);
  k_clsA<<<dim3(BB * HH / 4), 256, 0, stream>>>(x, cls_w1, cls_b1, clsh);
  k_clsB<<<dim3(BB * DD / 4), 256, 0, stream>>>(clsh, cls_w2, cls_b2, out);
  k_metrics<<<1, 256, 0, stream>>>(t_r2, t_dr, t_rs2, t_sd, out);
}

// Round 11
// 455.849 us; speedup vs baseline: 1.5040x; 1.0180x over previous
//
#include <hip/hip_runtime.h>
#include <math.h>

// Shapes (fixed)
#define BB 8
#define SEQ 2049
#define NT 2048
#define DD 1024
#define EE 8
#define SS 256
#define ESN 2048
#define HH 512

typedef __bf16 bf16x8 __attribute__((ext_vector_type(8)));
typedef float f32x4 __attribute__((ext_vector_type(4)));

__device__ __forceinline__ float gelu_f(float v) {
  return 0.5f * v * (1.0f + erff(v * 0.70710678118654752440f));
}
__device__ __forceinline__ float wave_sum(float v) {
#pragma unroll
  for (int off = 1; off < 64; off <<= 1) v += __shfl_xor(v, off);
  return v;
}
__device__ __forceinline__ unsigned short f2bf(float f) {
  unsigned int u = __float_as_uint(f);
  u = (u + 0x7fffu + ((u >> 16) & 1u)) >> 16;
  return (unsigned short)u;
}
__device__ __forceinline__ float bf2f(unsigned short h) {
  return __uint_as_float(((unsigned int)h) << 16);
}

// async 16B/lane global->LDS stage; lbase is wave-uniform, HW adds lane*16.
__device__ __forceinline__ void stage16(const unsigned short* g, unsigned short* lbase, int lane) {
#if __has_builtin(__builtin_amdgcn_global_load_lds)
  __builtin_amdgcn_global_load_lds((const __attribute__((address_space(1))) void*)g,
                                   (__attribute__((address_space(3))) void*)lbase, 16, 0, 0);
#else
  *(int4*)(lbase + lane * 8) = *(const int4*)g;
#endif
}

// XCD-aware bijective block remap (T1). All MFMA grids are divisible by 8, so
// q is exact and the map is bijective: XCD k receives a CONTIGUOUS chunk of
// the logical block space -> panel-sharing neighbor blocks hit the same L2.
__device__ __forceinline__ int3 xcd_map() {
  const int gx = gridDim.x, gy = gridDim.y;
  int bid = blockIdx.x + gx * (blockIdx.y + gy * blockIdx.z);
  const int q = (gx * gy * (int)gridDim.z) >> 3;
  bid = (bid & 7) * q + (bid >> 3);
  int3 r;
  r.x = bid % gx; bid /= gx;
  r.y = bid % gy;
  r.z = bid / gy;
  return r;
}

// ---- bf16 gemm_bt core (round-2/5 known-good sync): C[128x128]=A[m][k]*B[n][k]^T ----
// 256 threads = 4 waves (2x2 of 64x64). LDS tiles [128][32] bf16 linear.
// Single-buffered BK=32: stage -> barrier -> compute -> barrier.
// Compute is i-blocked (bq[4] + 2 af live) so __launch_bounds__(256,4) fits 128 regs.
__device__ __forceinline__ void gemm_core(const unsigned short* __restrict__ A,
                                          const unsigned short* __restrict__ B,
                                          int K, unsigned short* As, unsigned short* Bs,
                                          f32x4 acc[4][4]) {
  const int t = threadIdx.x;
  const int lane = t & 63, wave = t >> 6;
  const int srow = t >> 2, scol = (t & 3) * 8;
  const int fr = lane & 15, fk = (lane >> 4) * 8;
  const int wm = (wave >> 1) * 64, wn = (wave & 1) * 64;
  const unsigned short* a0 = A + (size_t)srow * K + scol;
  const unsigned short* a1 = A + (size_t)(srow + 64) * K + scol;
  const unsigned short* b0 = B + (size_t)srow * K + scol;
  const unsigned short* b1 = B + (size_t)(srow + 64) * K + scol;
  unsigned short* lA0 = As + wave * 512;
  unsigned short* lA1 = As + 2048 + wave * 512;
  unsigned short* lB0 = Bs + wave * 512;
  unsigned short* lB1 = Bs + 2048 + wave * 512;
  for (int k0 = 0; k0 < K; k0 += 32) {
    stage16(a0 + k0, lA0, lane);
    stage16(a1 + k0, lA1, lane);
    stage16(b0 + k0, lB0, lane);
    stage16(b1 + k0, lB1, lane);
    __syncthreads();  // drains vmcnt: staged tiles visible
    bf16x8 bq[4];
#pragma unroll
    for (int j = 0; j < 4; ++j)
      bq[j] = *(const bf16x8*)(Bs + (wn + j * 16 + fr) * 32 + fk);
#pragma unroll
    for (int ib = 0; ib < 2; ++ib) {
      bf16x8 afa = *(const bf16x8*)(As + (wm + (ib * 2) * 16 + fr) * 32 + fk);
      bf16x8 afb = *(const bf16x8*)(As + (wm + (ib * 2 + 1) * 16 + fr) * 32 + fk);
#pragma unroll
      for (int j = 0; j < 4; ++j)
        acc[ib * 2][j] = __builtin_amdgcn_mfma_f32_16x16x32_bf16(afa, bq[j], acc[ib * 2][j], 0, 0, 0);
#pragma unroll
      for (int j = 0; j < 4; ++j)
        acc[ib * 2 + 1][j] = __builtin_amdgcn_mfma_f32_16x16x32_bf16(afb, bq[j], acc[ib * 2 + 1][j], 0, 0, 0);
    }
    __syncthreads();  // all reads done before next stage overwrites
  }
}

#define ACC_INIT()                                        \
  f32x4 acc[4][4];                                        \
  _Pragma("unroll") for (int i = 0; i < 4; ++i)           \
  _Pragma("unroll") for (int j = 0; j < 4; ++j)           \
  _Pragma("unroll") for (int r = 0; r < 4; ++r) acc[i][j][r] = 0.f;

#define GEMM_EPI_VARS()                                   \
  const int lane = threadIdx.x & 63, wave = threadIdx.x >> 6; \
  const int wm = (wave >> 1) * 64, wn = (wave & 1) * 64;  \
  const int fr16 = lane & 15, r4 = (lane >> 4) << 2;

// logits -> E16[n][c] direct (32B runs) + ET[c][n] via chunked LDS transpose.
__global__ __launch_bounds__(256, 4) void k_logits_mfma(const unsigned short* __restrict__ Xb,
    const unsigned short* __restrict__ MT, unsigned short* __restrict__ E16,
    unsigned short* __restrict__ ET) {
  __shared__ unsigned short LDS[8448];
  ACC_INIT();
  const int3 bi = xcd_map();
  const int b = bi.z, m0 = bi.x * 128, n0 = bi.y * 128;
  gemm_core(Xb + ((size_t)b * NT + m0) * DD, MT + (size_t)n0 * DD, DD, LDS, LDS + 4096, acc);
  GEMM_EPI_VARS();
  const int t = threadIdx.x;
  unsigned short* o = E16 + (size_t)b * NT * ESN;
#pragma unroll
  for (int i = 0; i < 4; ++i)
#pragma unroll
    for (int j = 0; j < 4; ++j) {
      const int gmb = m0 + wm + i * 16 + r4;
      const int gn = n0 + wn + j * 16 + fr16;
      o[(size_t)(gmb + 0) * ESN + gn] = f2bf(expf(acc[i][j][0]));
      o[(size_t)(gmb + 1) * ESN + gn] = f2bf(expf(acc[i][j][1]));
      o[(size_t)(gmb + 2) * ESN + gn] = f2bf(expf(acc[i][j][2]));
      o[(size_t)(gmb + 3) * ESN + gn] = f2bf(expf(acc[i][j][3]));
    }
  // two 64-column chunks: chunk h handled by waves with wn == h*64
#pragma unroll
  for (int h = 0; h < 2; ++h) {
    if ((wn >> 6) == h) {
#pragma unroll
      for (int i = 0; i < 4; ++i)
#pragma unroll
        for (int j = 0; j < 4; ++j) {
          ushort4 pk;
          pk.x = f2bf(expf(acc[i][j][0]));
          pk.y = f2bf(expf(acc[i][j][1]));
          pk.z = f2bf(expf(acc[i][j][2]));
          pk.w = f2bf(expf(acc[i][j][3]));
          // T[n-local][m-local], stride 132 (8B-aligned rows)
          *(ushort4*)(LDS + (j * 16 + fr16) * 132 + wm + i * 16 + r4) = pk;
        }
    }
    __syncthreads();
#pragma unroll
    for (int p = 0; p < 4; ++p) {
      const int nl = p * 16 + (t >> 4);
      const int ml = (t & 15) * 8;
      int4 v = *(const int4*)(LDS + nl * 132 + ml);
      *(int4*)(ET + ((size_t)b * ESN + n0 + h * 64 + nl) * NT + m0 + ml) = v;
    }
    __syncthreads();
  }
}

__global__ __launch_bounds__(256, 4) void k_slotin_mfma(const unsigned short* __restrict__ ET,
    const unsigned short* __restrict__ XT, const float* __restrict__ cinv,
    unsigned short* __restrict__ SI) {
  __shared__ unsigned short LDS[8192];
  ACC_INIT();
  const int3 bi = xcd_map();
  const int b = bi.z, m0 = bi.x * 128, n0 = bi.y * 128;
  gemm_core(ET + ((size_t)b * ESN + m0) * NT, XT + ((size_t)b * DD + n0) * NT, NT,
            LDS, LDS + 4096, acc);
  GEMM_EPI_VARS();
#pragma unroll
  for (int i = 0; i < 4; ++i)
#pragma unroll
    for (int j = 0; j < 4; ++j) {
      const int gmb = m0 + wm + i * 16 + r4;
      const int gn = n0 + wn + j * 16 + fr16;
#pragma unroll
      for (int r = 0; r < 4; ++r)
        SI[((size_t)b * ESN + gmb + r) * DD + gn] = f2bf(acc[i][j][r] * cinv[b * ESN + gmb + r]);
    }
}

__global__ __launch_bounds__(256, 4) void k_ffn1_mfma(const unsigned short* __restrict__ SI,
    const unsigned short* __restrict__ w1b, const float* __restrict__ b1,
    unsigned short* __restrict__ H1) {
  __shared__ unsigned short LDS[8192];
  ACC_INIT();
  const int3 bi = xcd_map();
  const int z = bi.z, b = z >> 3, e = z & 7;
  const int m0 = bi.x * 128, n0 = bi.y * 128;
  gemm_core(SI + ((size_t)b * ESN + e * SS + m0) * DD, w1b + ((size_t)e * HH + n0) * DD,
            DD, LDS, LDS + 4096, acc);
  GEMM_EPI_VARS();
#pragma unroll
  for (int i = 0; i < 4; ++i)
#pragma unroll
    for (int j = 0; j < 4; ++j) {
      const int gmb = m0 + wm + i * 16 + r4;
      const int gn = n0 + wn + j * 16 + fr16;
      const float bias = b1[e * HH + gn];
#pragma unroll
      for (int r = 0; r < 4; ++r)
        H1[((size_t)(b * EE + e) * SS + gmb + r) * HH + gn] = f2bf(gelu_f(acc[i][j][r] + bias));
    }
}

// ffn2 -> SOT[d][c] via chunked LDS transpose (coalesced 256B rows)
__global__ __launch_bounds__(256, 4) void k_ffn2_mfma(const unsigned short* __restrict__ H1,
    const unsigned short* __restrict__ w2b, const float* __restrict__ b2,
    unsigned short* __restrict__ SOT) {
  __shared__ unsigned short LDS[8448];
  ACC_INIT();
  const int3 bi = xcd_map();
  const int z = bi.z, b = z >> 3, e = z & 7;
  const int m0 = bi.x * 128, n0 = bi.y * 128;   // m: s within expert, n: d
  gemm_core(H1 + ((size_t)(b * EE + e) * SS + m0) * HH, w2b + ((size_t)e * DD + n0) * HH,
            HH, LDS, LDS + 4096, acc);
  GEMM_EPI_VARS();
  const int t = threadIdx.x;
#pragma unroll
  for (int h = 0; h < 2; ++h) {
    if ((wn >> 6) == h) {
#pragma unroll
      for (int i = 0; i < 4; ++i)
#pragma unroll
        for (int j = 0; j < 4; ++j) {
          const float bias = b2[e * DD + n0 + wn + j * 16 + fr16];
          ushort4 pk;
          pk.x = f2bf(acc[i][j][0] + bias);
          pk.y = f2bf(acc[i][j][1] + bias);
          pk.z = f2bf(acc[i][j][2] + bias);
          pk.w = f2bf(acc[i][j][3] + bias);
          *(ushort4*)(LDS + (j * 16 + fr16) * 132 + wm + i * 16 + r4) = pk;
        }
    }
    __syncthreads();
#pragma unroll
    for (int p = 0; p < 4; ++p) {
      const int dl = p * 16 + (t >> 4);
      const int ml = (t & 15) * 8;
      int4 v = *(const int4*)(LDS + dl * 132 + ml);
      *(int4*)(SOT + ((size_t)b * DD + n0 + h * 64 + dl) * ESN + e * SS + m0 + ml) = v;
    }
    __syncthreads();
  }
}

__global__ __launch_bounds__(256, 4) void k_img_mfma(const unsigned short* __restrict__ E16,
    const unsigned short* __restrict__ SOT, const float* __restrict__ rinv,
    float* __restrict__ out) {
  __shared__ unsigned short LDS[8192];
  ACC_INIT();
  const int3 bi = xcd_map();
  const int b = bi.z, m0 = bi.x * 128, n0 = bi.y * 128;
  gemm_core(E16 + ((size_t)b * NT + m0) * ESN, SOT + ((size_t)b * DD + n0) * ESN,
            ESN, LDS, LDS + 4096, acc);
  GEMM_EPI_VARS();
#pragma unroll
  for (int i = 0; i < 4; ++i)
#pragma unroll
    for (int j = 0; j < 4; ++j) {
      const int gmb = m0 + wm + i * 16 + r4;
      const int gn = n0 + wn + j * 16 + fr16;
#pragma unroll
      for (int r = 0; r < 4; ++r)
        out[((size_t)b * SEQ + 1 + gmb + r) * DD + gn] = acc[i][j][r] * rinv[b * NT + gmb + r];
    }
}

// -------- packing --------
__global__ __launch_bounds__(256) void k_xnf(const float* __restrict__ x, float* __restrict__ xnf) {
  const int wid = blockIdx.x * 4 + (threadIdx.x >> 6);
  const int lane = threadIdx.x & 63;
  const int b = wid >> 11;
  const float* row = x + ((size_t)b * SEQ + 1 + (wid & (NT - 1))) * DD;
  float s = 0.f;
#pragma unroll
  for (int k = 0; k < DD / 64; ++k) { const float v = row[lane + k * 64]; s = fmaf(v, v, s); }
  s = wave_sum(s);
  if (lane == 0) xnf[wid] = 1.0f / fmaxf(sqrtf(s), 1e-12f);
}

// mu column-norm, 2-stage (round-9 single-stage was 114us at 1.4% occupancy)
__global__ __launch_bounds__(256) void k_munf_part(const float* __restrict__ mu,
    float* __restrict__ pm) {
  const int c = blockIdx.x * 256 + threadIdx.x;
  const int d0 = blockIdx.y * (DD / 16);
  float s = 0.f;
  for (int d = d0; d < d0 + DD / 16; ++d) {
    const float v = mu[(size_t)d * ESN + c];
    s = fmaf(v, v, s);
  }
  pm[blockIdx.y * ESN + c] = s;
}

__global__ __launch_bounds__(256) void k_munf_red(const float* __restrict__ pm,
    const float* __restrict__ scale, float* __restrict__ munf) {
  const int c = blockIdx.x * 256 + threadIdx.x;
  float s = 0.f;
#pragma unroll
  for (int k = 0; k < 16; ++k) s += pm[k * ESN + c];
  munf[c] = scale[0] / fmaxf(sqrtf(s), 1e-12f);
}

__global__ __launch_bounds__(256) void k_pack_x(const float* __restrict__ x,
    const float* __restrict__ xnf, unsigned short* __restrict__ Xb,
    unsigned short* __restrict__ XT) {
  __shared__ unsigned short tile[64][72];
  const int b = blockIdx.z, n0 = blockIdx.x * 64, d0 = blockIdx.y * 64;
  const int t = threadIdx.x, tr = t >> 2, tc = (t & 3) * 16;
  const float* s = x + ((size_t)b * SEQ + 1 + n0 + tr) * DD + d0 + tc;
  const float xs = xnf[b * NT + n0 + tr];
  unsigned short tmp[16];
#pragma unroll
  for (int j = 0; j < 16; j += 4) {
    float4 v = *(const float4*)(s + j);
    tmp[j] = f2bf(v.x * xs); tmp[j + 1] = f2bf(v.y * xs);
    tmp[j + 2] = f2bf(v.z * xs); tmp[j + 3] = f2bf(v.w * xs);
  }
  *(int4*)&tile[tr][tc] = *(int4*)tmp;
  *(int4*)&tile[tr][tc + 8] = *(int4*)(tmp + 8);
  unsigned short* xb = Xb + ((size_t)b * NT + n0 + tr) * DD + d0 + tc;
  *(int4*)xb = *(int4*)tmp;
  *(int4*)(xb + 8) = *(int4*)(tmp + 8);
  __syncthreads();
  unsigned short* d = XT + ((size_t)b * DD + d0 + tr) * NT + n0 + tc;
#pragma unroll
  for (int j = 0; j < 16; ++j) tmp[j] = tile[tc + j][tr];
  *(int4*)d = *(int4*)tmp;
  *(int4*)(d + 8) = *(int4*)(tmp + 8);
}

__global__ __launch_bounds__(256) void k_pack_mu(const float* __restrict__ mu,
    const float* __restrict__ munf, unsigned short* __restrict__ MT) {
  __shared__ unsigned short tile[64][72];
  const int d0 = blockIdx.x * 64, c0 = blockIdx.y * 64;
  const int t = threadIdx.x, tr = t >> 2, tc = (t & 3) * 16;
  const float* s = mu + (size_t)(d0 + tr) * ESN + c0 + tc;
  unsigned short tmp[16];
#pragma unroll
  for (int j = 0; j < 16; j += 4) {
    float4 v = *(const float4*)(s + j);
    tmp[j] = f2bf(v.x * munf[c0 + tc + j]);
    tmp[j + 1] = f2bf(v.y * munf[c0 + tc + j + 1]);
    tmp[j + 2] = f2bf(v.z * munf[c0 + tc + j + 2]);
    tmp[j + 3] = f2bf(v.w * munf[c0 + tc + j + 3]);
  }
  *(int4*)&tile[tr][tc] = *(int4*)tmp;
  *(int4*)&tile[tr][tc + 8] = *(int4*)(tmp + 8);
  __syncthreads();
  unsigned short* d = MT + (size_t)(c0 + tr) * DD + d0 + tc;
#pragma unroll
  for (int j = 0; j < 16; ++j) tmp[j] = tile[tc + j][tr];
  *(int4*)d = *(int4*)tmp;
  *(int4*)(d + 8) = *(int4*)(tmp + 8);
}

__global__ __launch_bounds__(256) void k_packw(const float* __restrict__ w,
    unsigned short* __restrict__ o, int n4) {
  const int i = blockIdx.x * 256 + threadIdx.x;
  if (i < n4) {
    float4 v = ((const float4*)w)[i];
    ushort4 u;
    u.x = f2bf(v.x); u.y = f2bf(v.y); u.z = f2bf(v.z); u.w = f2bf(v.w);
    ((ushort4*)o)[i] = u;
  }
}

// -------- softmax stats --------
__global__ __launch_bounds__(256) void k_rowstats_e(const unsigned short* __restrict__ E,
    float* __restrict__ rinv, float* __restrict__ t_r2, float* __restrict__ t_dr) {
  const int wid = blockIdx.x * 4 + (threadIdx.x >> 6);  // b*NT + n
  const int lane = threadIdx.x & 63;
  const int n = wid & (NT - 1);
  const unsigned short* row = E + (size_t)wid * ESN;
  float s1 = 0.f, s2 = 0.f;
#pragma unroll
  for (int it = 0; it < 4; ++it) {
    int4 v = *(const int4*)(row + it * 512 + lane * 8);
    const unsigned short* u = (const unsigned short*)&v;
#pragma unroll
    for (int j = 0; j < 8; ++j) { const float e = bf2f(u[j]); s1 += e; s2 = fmaf(e, e, s2); }
  }
  s1 = wave_sum(s1); s2 = wave_sum(s2);
  if (lane == 0) {
    const float ri = 1.0f / s1;
    rinv[wid] = ri;
    const float r2 = 1.0f / (s2 * ri * ri + 1e-9f);
    t_r2[wid] = r2;
    t_dr[wid] = bf2f(row[n]) * ri * r2;
  }
}

__global__ __launch_bounds__(256) void k_colstats(const unsigned short* __restrict__ ET,
    float* __restrict__ cinv, float* __restrict__ t_rs2, float* __restrict__ t_sd) {
  const int wid = blockIdx.x * 4 + (threadIdx.x >> 6);  // b*ESN + c
  const int lane = threadIdx.x & 63;
  const unsigned short* row = ET + (size_t)wid * NT;
  float s1 = 0.f, s2 = 0.f;
#pragma unroll
  for (int it = 0; it < 4; ++it) {
    int4 v = *(const int4*)(row + it * 512 + lane * 8);
    const unsigned short* u = (const unsigned short*)&v;
#pragma unroll
    for (int j = 0; j < 8; ++j) { const float e = bf2f(u[j]); s1 += e; s2 = fmaf(e, e, s2); }
  }
  s1 = wave_sum(s1); s2 = wave_sum(s2);
  if (lane == 0) {
    const float ci = 1.0f / s1;
    cinv[wid] = ci;
    const float rs2 = 1.0f / (s2 * ci * ci + 1e-9f);
    t_rs2[wid] = rs2;
    const int c = wid & (ESN - 1);
    t_sd[wid] = ((c % 257) == 0) ? rs2 : 0.f;
  }
}

// -------- cls path --------
__global__ __launch_bounds__(256) void k_clsA(const float* __restrict__ x,
    const float* __restrict__ w1, const float* __restrict__ b1, float* __restrict__ clsh) {
  const int wid = blockIdx.x * 4 + (threadIdx.x >> 6);
  const int lane = threadIdx.x & 63;
  const int b = wid >> 9, h = wid & (HH - 1);
  const float* xr = x + (size_t)b * SEQ * DD;
  const float* wr = w1 + (size_t)h * DD;
  float s = 0.f;
#pragma unroll
  for (int k = 0; k < DD / 64; ++k) s = fmaf(xr[lane + k * 64], wr[lane + k * 64], s);
  s = wave_sum(s);
  if (lane == 0) clsh[wid] = gelu_f(s + b1[h]);
}

__global__ __launch_bounds__(256) void k_clsB(const float* __restrict__ clsh,
    const float* __restrict__ w2, const float* __restrict__ b2, float* __restrict__ out) {
  const int wid = blockIdx.x * 4 + (threadIdx.x >> 6);
  const int lane = threadIdx.x & 63;
  const int b = wid >> 10, d = wid & (DD - 1);
  const float* hr = clsh + (size_t)b * HH;
  const float* wr = w2 + (size_t)d * HH;
  float s = 0.f;
#pragma unroll
  for (int k = 0; k < HH / 64; ++k) s = fmaf(hr[lane + k * 64], wr[lane + k * 64], s);
  s = wave_sum(s);
  if (lane == 0) out[(size_t)b * SEQ * DD + d] = s + b2[d];
}

__global__ __launch_bounds__(256) void k_metrics(const float* __restrict__ t_r2,
    const float* __restrict__ t_dr, const float* __restrict__ t_rs2,
    const float* __restrict__ t_sd, float* __restrict__ out) {
  __shared__ float sm[256];
  const int tid = threadIdx.x;
  float a = 0.f, b = 0.f, c = 0.f, d = 0.f;
  for (int i = tid; i < BB * NT; i += 256) { a += t_r2[i]; b += t_dr[i]; }
  for (int i = tid; i < BB * ESN; i += 256) { c += t_rs2[i]; d += t_sd[i]; }
  float vals[4] = {a, b, c, d};
  float res[4];
#pragma unroll
  for (int v = 0; v < 4; ++v) {
    sm[tid] = vals[v];
    __syncthreads();
    for (int s = 128; s > 0; s >>= 1) {
      if (tid < s) sm[tid] += sm[tid + s];
      __syncthreads();
    }
    res[v] = sm[0];
    __syncthreads();
  }
  if (tid == 0) {
    out[(size_t)BB * SEQ * DD] = (res[0] - res[1]) / 33538048.0f;
    out[(size_t)BB * SEQ * DD + 1] = (res[2] - res[3]) / 33538048.0f;
  }
}

extern "C" void kernel_launch(void* const* d_in, const int* in_sizes, int n_in,
                              void* d_out, int out_size, void* d_ws, size_t ws_size,
                              hipStream_t stream) {
  const float* x      = (const float*)d_in[0];
  const float* mu     = (const float*)d_in[1];
  const float* scale  = (const float*)d_in[2];
  const float* cls_w1 = (const float*)d_in[3];
  const float* cls_b1 = (const float*)d_in[4];
  const float* cls_w2 = (const float*)d_in[5];
  const float* cls_b2 = (const float*)d_in[6];
  const float* w1     = (const float*)d_in[7];
  const float* b1     = (const float*)d_in[8];
  const float* w2     = (const float*)d_in[9];
  const float* b2     = (const float*)d_in[10];
  float* out = (float*)d_out;

  // workspace plan (bytes), aliasing by lifetime:
  char* W = (char*)d_ws;
  unsigned short* XT  = (unsigned short*)(W);              // 32MB; H1 aliases after slotin
  unsigned short* Xb  = (unsigned short*)(W + 33554432);   // 32MB; SOT aliases after logits
  unsigned short* MT  = (unsigned short*)(W + 67108864);   //  4MB
  unsigned short* E16 = (unsigned short*)(W + 71303168);   // 64MB (written by logits; munf partials alias before that)
  unsigned short* ET  = (unsigned short*)(W + 138412032);  // 64MB; w1b/w2b alias after slotin
  unsigned short* SI  = (unsigned short*)(W + 205520896);  // 32MB
  unsigned short* H1  = (unsigned short*)(W);              // 16MB (alias XT)
  unsigned short* SOT = (unsigned short*)(W + 33554432);   // 32MB (alias Xb)
  unsigned short* w1b = (unsigned short*)(W + 138412032);  //  8MB (alias ET)
  unsigned short* w2b = (unsigned short*)(W + 146800640);  //  8MB (alias ET)
  float* pmunf = (float*)(W + 71303168);                   // 128KB (alias E16, dead before logits)
  float* F = (float*)(W + 239075328);
  float* xnf   = F;
  float* munf  = F + 16384;
  float* rinv  = F + 18432;
  float* t_r2  = F + 34816;
  float* t_dr  = F + 51200;
  float* cinv  = F + 67584;
  float* t_rs2 = F + 83968;
  float* t_sd  = F + 100352;
  float* clsh  = F + 116736;

  k_xnf<<<dim3(BB * NT / 4), 256, 0, stream>>>(x, xnf);
  k_munf_part<<<dim3(ESN / 256, 16), 256, 0, stream>>>(mu, pmunf);
  k_munf_red<<<dim3(ESN / 256), 256, 0, stream>>>(pmunf, scale, munf);
  k_pack_x<<<dim3(NT / 64, DD / 64, BB), 256, 0, stream>>>(x, xnf, Xb, XT);
  k_pack_mu<<<dim3(DD / 64, ESN / 64), 256, 0, stream>>>(mu, munf, MT);
  k_logits_mfma<<<dim3(NT / 128, ESN / 128, BB), 256, 0, stream>>>(Xb, MT, E16, ET);
  k_rowstats_e<<<dim3(BB * NT / 4), 256, 0, stream>>>(E16, rinv, t_r2, t_dr);
  k_colstats<<<dim3(BB * ESN / 4), 256, 0, stream>>>(ET, cinv, t_rs2, t_sd);
  k_slotin_mfma<<<dim3(ESN / 128, DD / 128, BB), 256, 0, stream>>>(ET, XT, cinv, SI);
  k_packw<<<dim3(EE * HH * DD / 4 / 256), 256, 0, stream>>>(w1, w1b, EE * HH * DD / 4);
  k_packw<<<dim3(EE * DD * HH / 4 / 256), 256, 0, stream>>>(w2, w2b, EE * DD * HH / 4);
  k_ffn1_mfma<<<dim3(SS / 128, HH / 128, BB * EE), 256, 0, stream>>>(SI, w1b, b1, H1);
  k_ffn2_mfma<<<dim3(SS / 128, DD / 128, BB * EE), 256, 0, stream>>>(H1, w2b, b2, SOT);
  k_img_mfma<<<dim3(NT / 128, DD / 128, BB), 256, 0, stream>>>(E16, SOT, rinv, out);
  k_clsA<<<dim3(BB * HH / 4), 256, 0, stream>>>(x, cls_w1, cls_b1, clsh);
  k_clsB<<<dim3(BB * DD / 4), 256, 0, stream>>>(clsh, cls_w2, cls_b2, out);
  k_metrics<<<1, 256, 0, stream>>>(t_r2, t_dr, t_rs2, t_sd, out);
}

// Round 12
// 447.151 us; speedup vs baseline: 1.5333x; 1.0195x over previous
//
#include <hip/hip_runtime.h>
#include <math.h>

// Shapes (fixed)
#define BB 8
#define SEQ 2049
#define NT 2048
#define DD 1024
#define EE 8
#define SS 256
#define ESN 2048
#define HH 512

typedef __bf16 bf16x8 __attribute__((ext_vector_type(8)));
typedef float f32x4 __attribute__((ext_vector_type(4)));

__device__ __forceinline__ float gelu_f(float v) {
  return 0.5f * v * (1.0f + erff(v * 0.70710678118654752440f));
}
__device__ __forceinline__ float wave_sum(float v) {
#pragma unroll
  for (int off = 1; off < 64; off <<= 1) v += __shfl_xor(v, off);
  return v;
}
__device__ __forceinline__ unsigned short f2bf(float f) {
  unsigned int u = __float_as_uint(f);
  u = (u + 0x7fffu + ((u >> 16) & 1u)) >> 16;
  return (unsigned short)u;
}
__device__ __forceinline__ float bf2f(unsigned short h) {
  return __uint_as_float(((unsigned int)h) << 16);
}

// async 16B/lane global->LDS stage; lbase is wave-uniform, HW adds lane*16.
__device__ __forceinline__ void stage16(const unsigned short* g, unsigned short* lbase, int lane) {
#if __has_builtin(__builtin_amdgcn_global_load_lds)
  __builtin_amdgcn_global_load_lds((const __attribute__((address_space(1))) void*)g,
                                   (__attribute__((address_space(3))) void*)lbase, 16, 0, 0);
#else
  *(int4*)(lbase + lane * 8) = *(const int4*)g;
#endif
}

// XCD-aware bijective block remap (T1). All MFMA grids are divisible by 8.
__device__ __forceinline__ int3 xcd_map() {
  const int gx = gridDim.x, gy = gridDim.y;
  int bid = blockIdx.x + gx * (blockIdx.y + gy * blockIdx.z);
  const int q = (gx * gy * (int)gridDim.z) >> 3;
  bid = (bid & 7) * q + (bid >> 3);
  int3 r;
  r.x = bid % gx; bid /= gx;
  r.y = bid % gy;
  r.z = bid / gy;
  return r;
}

// ---- bf16 gemm_bt core: C[128x128]=A[m][k]*B[n][k]^T, K%64==0 ----
// Round-2/5 sync structure (stage -> barrier -> compute -> barrier), BK=64:
// one barrier pair per 64 K (vs 32), and 8-lane x 16B = 128B contiguous
// staging segments per row. LDS 32KB: A rows [128][64] at r*64, B at +8192.
// Compute i-blocked (bq[4] + 2 af live) so __launch_bounds__(256,4) fits 128 regs.
__device__ __forceinline__ void gemm_core(const unsigned short* __restrict__ A,
                                          const unsigned short* __restrict__ B,
                                          int K, unsigned short* LDS, f32x4 acc[4][4]) {
  const int t = threadIdx.x;
  const int lane = t & 63, wave = t >> 6;
  const int srow = t >> 3, scol = (t & 7) * 8;   // 8 lanes cover one 128B row
  const int fr = lane & 15, fk = (lane >> 4) * 8;
  const int wm = (wave >> 1) * 64, wn = (wave & 1) * 64;
  const unsigned short* ap = A + (size_t)srow * K + scol;
  const unsigned short* bp = B + (size_t)srow * K + scol;
  unsigned short* dA = LDS + wave * 512;
  unsigned short* dB = LDS + 8192 + wave * 512;
  for (int k0 = 0; k0 < K; k0 += 64) {
#pragma unroll
    for (int q = 0; q < 4; ++q) {
      stage16(ap + (size_t)(q * 32) * K + k0, dA + q * 2048, lane);
      stage16(bp + (size_t)(q * 32) * K + k0, dB + q * 2048, lane);
    }
    __syncthreads();  // drains vmcnt: staged tiles visible
#pragma unroll
    for (int kk = 0; kk < 2; ++kk) {
      bf16x8 bq[4];
#pragma unroll
      for (int j = 0; j < 4; ++j)
        bq[j] = *(const bf16x8*)(LDS + 8192 + (wn + j * 16 + fr) * 64 + kk * 32 + fk);
#pragma unroll
      for (int ib = 0; ib < 2; ++ib) {
        bf16x8 afa = *(const bf16x8*)(LDS + (wm + (ib * 2) * 16 + fr) * 64 + kk * 32 + fk);
        bf16x8 afb = *(const bf16x8*)(LDS + (wm + (ib * 2 + 1) * 16 + fr) * 64 + kk * 32 + fk);
#pragma unroll
        for (int j = 0; j < 4; ++j)
          acc[ib * 2][j] = __builtin_amdgcn_mfma_f32_16x16x32_bf16(afa, bq[j], acc[ib * 2][j], 0, 0, 0);
#pragma unroll
        for (int j = 0; j < 4; ++j)
          acc[ib * 2 + 1][j] = __builtin_amdgcn_mfma_f32_16x16x32_bf16(afb, bq[j], acc[ib * 2 + 1][j], 0, 0, 0);
      }
    }
    __syncthreads();  // all reads done before next stage overwrites
  }
}

#define ACC_INIT()                                        \
  f32x4 acc[4][4];                                        \
  _Pragma("unroll") for (int i = 0; i < 4; ++i)           \
  _Pragma("unroll") for (int j = 0; j < 4; ++j)           \
  _Pragma("unroll") for (int r = 0; r < 4; ++r) acc[i][j][r] = 0.f;

#define GEMM_EPI_VARS()                                   \
  const int lane = threadIdx.x & 63, wave = threadIdx.x >> 6; \
  const int wm = (wave >> 1) * 64, wn = (wave & 1) * 64;  \
  const int fr16 = lane & 15, r4 = (lane >> 4) << 2;

// logits -> E16[n][c] direct (32B runs) + ET[c][n] via chunked LDS transpose.
__global__ __launch_bounds__(256, 4) void k_logits_mfma(const unsigned short* __restrict__ Xb,
    const unsigned short* __restrict__ MT, unsigned short* __restrict__ E16,
    unsigned short* __restrict__ ET) {
  __shared__ unsigned short LDS[16384];
  ACC_INIT();
  const int3 bi = xcd_map();
  const int b = bi.z, m0 = bi.x * 128, n0 = bi.y * 128;
  gemm_core(Xb + ((size_t)b * NT + m0) * DD, MT + (size_t)n0 * DD, DD, LDS, acc);
  GEMM_EPI_VARS();
  const int t = threadIdx.x;
  unsigned short* o = E16 + (size_t)b * NT * ESN;
#pragma unroll
  for (int i = 0; i < 4; ++i)
#pragma unroll
    for (int j = 0; j < 4; ++j) {
      const int gmb = m0 + wm + i * 16 + r4;
      const int gn = n0 + wn + j * 16 + fr16;
      o[(size_t)(gmb + 0) * ESN + gn] = f2bf(expf(acc[i][j][0]));
      o[(size_t)(gmb + 1) * ESN + gn] = f2bf(expf(acc[i][j][1]));
      o[(size_t)(gmb + 2) * ESN + gn] = f2bf(expf(acc[i][j][2]));
      o[(size_t)(gmb + 3) * ESN + gn] = f2bf(expf(acc[i][j][3]));
    }
  // two 64-column chunks: chunk h handled by waves with wn == h*64
#pragma unroll
  for (int h = 0; h < 2; ++h) {
    if ((wn >> 6) == h) {
#pragma unroll
      for (int i = 0; i < 4; ++i)
#pragma unroll
        for (int j = 0; j < 4; ++j) {
          ushort4 pk;
          pk.x = f2bf(expf(acc[i][j][0]));
          pk.y = f2bf(expf(acc[i][j][1]));
          pk.z = f2bf(expf(acc[i][j][2]));
          pk.w = f2bf(expf(acc[i][j][3]));
          // T[n-local][m-local], stride 132 (8B-aligned rows)
          *(ushort4*)(LDS + (j * 16 + fr16) * 132 + wm + i * 16 + r4) = pk;
        }
    }
    __syncthreads();
#pragma unroll
    for (int p = 0; p < 4; ++p) {
      const int nl = p * 16 + (t >> 4);
      const int ml = (t & 15) * 8;
      int4 v = *(const int4*)(LDS + nl * 132 + ml);
      *(int4*)(ET + ((size_t)b * ESN + n0 + h * 64 + nl) * NT + m0 + ml) = v;
    }
    __syncthreads();
  }
}

__global__ __launch_bounds__(256, 4) void k_slotin_mfma(const unsigned short* __restrict__ ET,
    const unsigned short* __restrict__ XT, const float* __restrict__ cinv,
    unsigned short* __restrict__ SI) {
  __shared__ unsigned short LDS[16384];
  ACC_INIT();
  const int3 bi = xcd_map();
  const int b = bi.z, m0 = bi.x * 128, n0 = bi.y * 128;
  gemm_core(ET + ((size_t)b * ESN + m0) * NT, XT + ((size_t)b * DD + n0) * NT, NT, LDS, acc);
  GEMM_EPI_VARS();
#pragma unroll
  for (int i = 0; i < 4; ++i)
#pragma unroll
    for (int j = 0; j < 4; ++j) {
      const int gmb = m0 + wm + i * 16 + r4;
      const int gn = n0 + wn + j * 16 + fr16;
#pragma unroll
      for (int r = 0; r < 4; ++r)
        SI[((size_t)b * ESN + gmb + r) * DD + gn] = f2bf(acc[i][j][r] * cinv[b * ESN + gmb + r]);
    }
}

__global__ __launch_bounds__(256, 4) void k_ffn1_mfma(const unsigned short* __restrict__ SI,
    const unsigned short* __restrict__ w1b, const float* __restrict__ b1,
    unsigned short* __restrict__ H1) {
  __shared__ unsigned short LDS[16384];
  ACC_INIT();
  const int3 bi = xcd_map();
  const int z = bi.z, b = z >> 3, e = z & 7;
  const int m0 = bi.x * 128, n0 = bi.y * 128;
  gemm_core(SI + ((size_t)b * ESN + e * SS + m0) * DD, w1b + ((size_t)e * HH + n0) * DD,
            DD, LDS, acc);
  GEMM_EPI_VARS();
#pragma unroll
  for (int i = 0; i < 4; ++i)
#pragma unroll
    for (int j = 0; j < 4; ++j) {
      const int gmb = m0 + wm + i * 16 + r4;
      const int gn = n0 + wn + j * 16 + fr16;
      const float bias = b1[e * HH + gn];
#pragma unroll
      for (int r = 0; r < 4; ++r)
        H1[((size_t)(b * EE + e) * SS + gmb + r) * HH + gn] = f2bf(gelu_f(acc[i][j][r] + bias));
    }
}

// ffn2 -> SOT[d][c] via chunked LDS transpose (coalesced 256B rows)
__global__ __launch_bounds__(256, 4) void k_ffn2_mfma(const unsigned short* __restrict__ H1,
    const unsigned short* __restrict__ w2b, const float* __restrict__ b2,
    unsigned short* __restrict__ SOT) {
  __shared__ unsigned short LDS[16384];
  ACC_INIT();
  const int3 bi = xcd_map();
  const int z = bi.z, b = z >> 3, e = z & 7;
  const int m0 = bi.x * 128, n0 = bi.y * 128;   // m: s within expert, n: d
  gemm_core(H1 + ((size_t)(b * EE + e) * SS + m0) * HH, w2b + ((size_t)e * DD + n0) * HH,
            HH, LDS, acc);
  GEMM_EPI_VARS();
  const int t = threadIdx.x;
#pragma unroll
  for (int h = 0; h < 2; ++h) {
    if ((wn >> 6) == h) {
#pragma unroll
      for (int i = 0; i < 4; ++i)
#pragma unroll
        for (int j = 0; j < 4; ++j) {
          const float bias = b2[e * DD + n0 + wn + j * 16 + fr16];
          ushort4 pk;
          pk.x = f2bf(acc[i][j][0] + bias);
          pk.y = f2bf(acc[i][j][1] + bias);
          pk.z = f2bf(acc[i][j][2] + bias);
          pk.w = f2bf(acc[i][j][3] + bias);
          *(ushort4*)(LDS + (j * 16 + fr16) * 132 + wm + i * 16 + r4) = pk;
        }
    }
    __syncthreads();
#pragma unroll
    for (int p = 0; p < 4; ++p) {
      const int dl = p * 16 + (t >> 4);
      const int ml = (t & 15) * 8;
      int4 v = *(const int4*)(LDS + dl * 132 + ml);
      *(int4*)(SOT + ((size_t)b * DD + n0 + h * 64 + dl) * ESN + e * SS + m0 + ml) = v;
    }
    __syncthreads();
  }
}

__global__ __launch_bounds__(256, 4) void k_img_mfma(const unsigned short* __restrict__ E16,
    const unsigned short* __restrict__ SOT, const float* __restrict__ rinv,
    float* __restrict__ out) {
  __shared__ unsigned short LDS[16384];
  ACC_INIT();
  const int3 bi = xcd_map();
  const int b = bi.z, m0 = bi.x * 128, n0 = bi.y * 128;
  gemm_core(E16 + ((size_t)b * NT + m0) * ESN, SOT + ((size_t)b * DD + n0) * ESN,
            ESN, LDS, acc);
  GEMM_EPI_VARS();
#pragma unroll
  for (int i = 0; i < 4; ++i)
#pragma unroll
    for (int j = 0; j < 4; ++j) {
      const int gmb = m0 + wm + i * 16 + r4;
      const int gn = n0 + wn + j * 16 + fr16;
#pragma unroll
      for (int r = 0; r < 4; ++r)
        out[((size_t)b * SEQ + 1 + gmb + r) * DD + gn] = acc[i][j][r] * rinv[b * NT + gmb + r];
    }
}

// -------- packing --------
__global__ __launch_bounds__(256) void k_xnf(const float* __restrict__ x, float* __restrict__ xnf) {
  const int wid = blockIdx.x * 4 + (threadIdx.x >> 6);
  const int lane = threadIdx.x & 63;
  const int b = wid >> 11;
  const float* row = x + ((size_t)b * SEQ + 1 + (wid & (NT - 1))) * DD;
  float s = 0.f;
#pragma unroll
  for (int k = 0; k < DD / 64; ++k) { const float v = row[lane + k * 64]; s = fmaf(v, v, s); }
  s = wave_sum(s);
  if (lane == 0) xnf[wid] = 1.0f / fmaxf(sqrtf(s), 1e-12f);
}

// mu column-norm, 2-stage
__global__ __launch_bounds__(256) void k_munf_part(const float* __restrict__ mu,
    float* __restrict__ pm) {
  const int c = blockIdx.x * 256 + threadIdx.x;
  const int d0 = blockIdx.y * (DD / 16);
  float s = 0.f;
  for (int d = d0; d < d0 + DD / 16; ++d) {
    const float v = mu[(size_t)d * ESN + c];
    s = fmaf(v, v, s);
  }
  pm[blockIdx.y * ESN + c] = s;
}

__global__ __launch_bounds__(256) void k_munf_red(const float* __restrict__ pm,
    const float* __restrict__ scale, float* __restrict__ munf) {
  const int c = blockIdx.x * 256 + threadIdx.x;
  float s = 0.f;
#pragma unroll
  for (int k = 0; k < 16; ++k) s += pm[k * ESN + c];
  munf[c] = scale[0] / fmaxf(sqrtf(s), 1e-12f);
}

__global__ __launch_bounds__(256) void k_pack_x(const float* __restrict__ x,
    const float* __restrict__ xnf, unsigned short* __restrict__ Xb,
    unsigned short* __restrict__ XT) {
  __shared__ unsigned short tile[64][72];
  const int b = blockIdx.z, n0 = blockIdx.x * 64, d0 = blockIdx.y * 64;
  const int t = threadIdx.x, tr = t >> 2, tc = (t & 3) * 16;
  const float* s = x + ((size_t)b * SEQ + 1 + n0 + tr) * DD + d0 + tc;
  const float xs = xnf[b * NT + n0 + tr];
  unsigned short tmp[16];
#pragma unroll
  for (int j = 0; j < 16; j += 4) {
    float4 v = *(const float4*)(s + j);
    tmp[j] = f2bf(v.x * xs); tmp[j + 1] = f2bf(v.y * xs);
    tmp[j + 2] = f2bf(v.z * xs); tmp[j + 3] = f2bf(v.w * xs);
  }
  *(int4*)&tile[tr][tc] = *(int4*)tmp;
  *(int4*)&tile[tr][tc + 8] = *(int4*)(tmp + 8);
  unsigned short* xb = Xb + ((size_t)b * NT + n0 + tr) * DD + d0 + tc;
  *(int4*)xb = *(int4*)tmp;
  *(int4*)(xb + 8) = *(int4*)(tmp + 8);
  __syncthreads();
  unsigned short* d = XT + ((size_t)b * DD + d0 + tr) * NT + n0 + tc;
#pragma unroll
  for (int j = 0; j < 16; ++j) tmp[j] = tile[tc + j][tr];
  *(int4*)d = *(int4*)tmp;
  *(int4*)(d + 8) = *(int4*)(tmp + 8);
}

__global__ __launch_bounds__(256) void k_pack_mu(const float* __restrict__ mu,
    const float* __restrict__ munf, unsigned short* __restrict__ MT) {
  __shared__ unsigned short tile[64][72];
  const int d0 = blockIdx.x * 64, c0 = blockIdx.y * 64;
  const int t = threadIdx.x, tr = t >> 2, tc = (t & 3) * 16;
  const float* s = mu + (size_t)(d0 + tr) * ESN + c0 + tc;
  unsigned short tmp[16];
#pragma unroll
  for (int j = 0; j < 16; j += 4) {
    float4 v = *(const float4*)(s + j);
    tmp[j] = f2bf(v.x * munf[c0 + tc + j]);
    tmp[j + 1] = f2bf(v.y * munf[c0 + tc + j + 1]);
    tmp[j + 2] = f2bf(v.z * munf[c0 + tc + j + 2]);
    tmp[j + 3] = f2bf(v.w * munf[c0 + tc + j + 3]);
  }
  *(int4*)&tile[tr][tc] = *(int4*)tmp;
  *(int4*)&tile[tr][tc + 8] = *(int4*)(tmp + 8);
  __syncthreads();
  unsigned short* d = MT + (size_t)(c0 + tr) * DD + d0 + tc;
#pragma unroll
  for (int j = 0; j < 16; ++j) tmp[j] = tile[tc + j][tr];
  *(int4*)d = *(int4*)tmp;
  *(int4*)(d + 8) = *(int4*)(tmp + 8);
}

__global__ __launch_bounds__(256) void k_packw(const float* __restrict__ w,
    unsigned short* __restrict__ o, int n4) {
  const int i = blockIdx.x * 256 + threadIdx.x;
  if (i < n4) {
    float4 v = ((const float4*)w)[i];
    ushort4 u;
    u.x = f2bf(v.x); u.y = f2bf(v.y); u.z = f2bf(v.z); u.w = f2bf(v.w);
    ((ushort4*)o)[i] = u;
  }
}

// -------- softmax stats --------
__global__ __launch_bounds__(256) void k_rowstats_e(const unsigned short* __restrict__ E,
    float* __restrict__ rinv, float* __restrict__ t_r2, float* __restrict__ t_dr) {
  const int wid = blockIdx.x * 4 + (threadIdx.x >> 6);  // b*NT + n
  const int lane = threadIdx.x & 63;
  const int n = wid & (NT - 1);
  const unsigned short* row = E + (size_t)wid * ESN;
  float s1 = 0.f, s2 = 0.f;
#pragma unroll
  for (int it = 0; it < 4; ++it) {
    int4 v = *(const int4*)(row + it * 512 + lane * 8);
    const unsigned short* u = (const unsigned short*)&v;
#pragma unroll
    for (int j = 0; j < 8; ++j) { const float e = bf2f(u[j]); s1 += e; s2 = fmaf(e, e, s2); }
  }
  s1 = wave_sum(s1); s2 = wave_sum(s2);
  if (lane == 0) {
    const float ri = 1.0f / s1;
    rinv[wid] = ri;
    const float r2 = 1.0f / (s2 * ri * ri + 1e-9f);
    t_r2[wid] = r2;
    t_dr[wid] = bf2f(row[n]) * ri * r2;
  }
}

__global__ __launch_bounds__(256) void k_colstats(const unsigned short* __restrict__ ET,
    float* __restrict__ cinv, float* __restrict__ t_rs2, float* __restrict__ t_sd) {
  const int wid = blockIdx.x * 4 + (threadIdx.x >> 6);  // b*ESN + c
  const int lane = threadIdx.x & 63;
  const unsigned short* row = ET + (size_t)wid * NT;
  float s1 = 0.f, s2 = 0.f;
#pragma unroll
  for (int it = 0; it < 4; ++it) {
    int4 v = *(const int4*)(row + it * 512 + lane * 8);
    const unsigned short* u = (const unsigned short*)&v;
#pragma unroll
    for (int j = 0; j < 8; ++j) { const float e = bf2f(u[j]); s1 += e; s2 = fmaf(e, e, s2); }
  }
  s1 = wave_sum(s1); s2 = wave_sum(s2);
  if (lane == 0) {
    const float ci = 1.0f / s1;
    cinv[wid] = ci;
    const float rs2 = 1.0f / (s2 * ci * ci + 1e-9f);
    t_rs2[wid] = rs2;
    const int c = wid & (ESN - 1);
    t_sd[wid] = ((c % 257) == 0) ? rs2 : 0.f;
  }
}

// -------- cls path --------
__global__ __launch_bounds__(256) void k_clsA(const float* __restrict__ x,
    const float* __restrict__ w1, const float* __restrict__ b1, float* __restrict__ clsh) {
  const int wid = blockIdx.x * 4 + (threadIdx.x >> 6);
  const int lane = threadIdx.x & 63;
  const int b = wid >> 9, h = wid & (HH - 1);
  const float* xr = x + (size_t)b * SEQ * DD;
  const float* wr = w1 + (size_t)h * DD;
  float s = 0.f;
#pragma unroll
  for (int k = 0; k < DD / 64; ++k) s = fmaf(xr[lane + k * 64], wr[lane + k * 64], s);
  s = wave_sum(s);
  if (lane == 0) clsh[wid] = gelu_f(s + b1[h]);
}

__global__ __launch_bounds__(256) void k_clsB(const float* __restrict__ clsh,
    const float* __restrict__ w2, const float* __restrict__ b2, float* __restrict__ out) {
  const int wid = blockIdx.x * 4 + (threadIdx.x >> 6);
  const int lane = threadIdx.x & 63;
  const int b = wid >> 10, d = wid & (DD - 1);
  const float* hr = clsh + (size_t)b * HH;
  const float* wr = w2 + (size_t)d * HH;
  float s = 0.f;
#pragma unroll
  for (int k = 0; k < HH / 64; ++k) s = fmaf(hr[lane + k * 64], wr[lane + k * 64], s);
  s = wave_sum(s);
  if (lane == 0) out[(size_t)b * SEQ * DD + d] = s + b2[d];
}

__global__ __launch_bounds__(256) void k_metrics(const float* __restrict__ t_r2,
    const float* __restrict__ t_dr, const float* __restrict__ t_rs2,
    const float* __restrict__ t_sd, float* __restrict__ out) {
  __shared__ float sm[256];
  const int tid = threadIdx.x;
  float a = 0.f, b = 0.f, c = 0.f, d = 0.f;
  for (int i = tid; i < BB * NT; i += 256) { a += t_r2[i]; b += t_dr[i]; }
  for (int i = tid; i < BB * ESN; i += 256) { c += t_rs2[i]; d += t_sd[i]; }
  float vals[4] = {a, b, c, d};
  float res[4];
#pragma unroll
  for (int v = 0; v < 4; ++v) {
    sm[tid] = vals[v];
    __syncthreads();
    for (int s = 128; s > 0; s >>= 1) {
      if (tid < s) sm[tid] += sm[tid + s];
      __syncthreads();
    }
    res[v] = sm[0];
    __syncthreads();
  }
  if (tid == 0) {
    out[(size_t)BB * SEQ * DD] = (res[0] - res[1]) / 33538048.0f;
    out[(size_t)BB * SEQ * DD + 1] = (res[2] - res[3]) / 33538048.0f;
  }
}

extern "C" void kernel_launch(void* const* d_in, const int* in_sizes, int n_in,
                              void* d_out, int out_size, void* d_ws, size_t ws_size,
                              hipStream_t stream) {
  const float* x      = (const float*)d_in[0];
  const float* mu     = (const float*)d_in[1];
  const float* scale  = (const float*)d_in[2];
  const float* cls_w1 = (const float*)d_in[3];
  const float* cls_b1 = (const float*)d_in[4];
  const float* cls_w2 = (const float*)d_in[5];
  const float* cls_b2 = (const float*)d_in[6];
  const float* w1     = (const float*)d_in[7];
  const float* b1     = (const float*)d_in[8];
  const float* w2     = (const float*)d_in[9];
  const float* b2     = (const float*)d_in[10];
  float* out = (float*)d_out;

  // workspace plan (bytes), aliasing by lifetime:
  char* W = (char*)d_ws;
  unsigned short* XT  = (unsigned short*)(W);              // 32MB; H1 aliases after slotin
  unsigned short* Xb  = (unsigned short*)(W + 33554432);   // 32MB; SOT aliases after logits
  unsigned short* MT  = (unsigned short*)(W + 67108864);   //  4MB
  unsigned short* E16 = (unsigned short*)(W + 71303168);   // 64MB (written by logits; munf partials alias before that)
  unsigned short* ET  = (unsigned short*)(W + 138412032);  // 64MB; w1b/w2b alias after slotin
  unsigned short* SI  = (unsigned short*)(W + 205520896);  // 32MB
  unsigned short* H1  = (unsigned short*)(W);              // 16MB (alias XT)
  unsigned short* SOT = (unsigned short*)(W + 33554432);   // 32MB (alias Xb)
  unsigned short* w1b = (unsigned short*)(W + 138412032);  //  8MB (alias ET)
  unsigned short* w2b = (unsigned short*)(W + 146800640);  //  8MB (alias ET)
  float* pmunf = (float*)(W + 71303168);                   // 128KB (alias E16, dead before logits)
  float* F = (float*)(W + 239075328);
  float* xnf   = F;
  float* munf  = F + 16384;
  float* rinv  = F + 18432;
  float* t_r2  = F + 34816;
  float* t_dr  = F + 51200;
  float* cinv  = F + 67584;
  float* t_rs2 = F + 83968;
  float* t_sd  = F + 100352;
  float* clsh  = F + 116736;

  k_xnf<<<dim3(BB * NT / 4), 256, 0, stream>>>(x, xnf);
  k_munf_part<<<dim3(ESN / 256, 16), 256, 0, stream>>>(mu, pmunf);
  k_munf_red<<<dim3(ESN / 256), 256, 0, stream>>>(pmunf, scale, munf);
  k_pack_x<<<dim3(NT / 64, DD / 64, BB), 256, 0, stream>>>(x, xnf, Xb, XT);
  k_pack_mu<<<dim3(DD / 64, ESN / 64), 256, 0, stream>>>(mu, munf, MT);
  k_logits_mfma<<<dim3(NT / 128, ESN / 128, BB), 256, 0, stream>>>(Xb, MT, E16, ET);
  k_rowstats_e<<<dim3(BB * NT / 4), 256, 0, stream>>>(E16, rinv, t_r2, t_dr);
  k_colstats<<<dim3(BB * ESN / 4), 256, 0, stream>>>(ET, cinv, t_rs2, t_sd);
  k_slotin_mfma<<<dim3(ESN / 128, DD / 128, BB), 256, 0, stream>>>(ET, XT, cinv, SI);
  k_packw<<<dim3(EE * HH * DD / 4 / 256), 256, 0, stream>>>(w1, w1b, EE * HH * DD / 4);
  k_packw<<<dim3(EE * DD * HH / 4 / 256), 256, 0, stream>>>(w2, w2b, EE * DD * HH / 4);
  k_ffn1_mfma<<<dim3(SS / 128, HH / 128, BB * EE), 256, 0, stream>>>(SI, w1b, b1, H1);
  k_ffn2_mfma<<<dim3(SS / 128, DD / 128, BB * EE), 256, 0, stream>>>(H1, w2b, b2, SOT);
  k_img_mfma<<<dim3(NT / 128, DD / 128, BB), 256, 0, stream>>>(E16, SOT, rinv, out);
  k_clsA<<<dim3(BB * HH / 4), 256, 0, stream>>>(x, cls_w1, cls_b1, clsh);
  k_clsB<<<dim3(BB * DD / 4), 256, 0, stream>>>(clsh, cls_w2, cls_b2, out);
  k_metrics<<<1, 256, 0, stream>>>(t_r2, t_dr, t_rs2, t_sd, out);
}

// Round 13
// 424.763 us; speedup vs baseline: 1.6141x; 1.0527x over previous
//
#include <hip/hip_runtime.h>
#include <math.h>

// Shapes (fixed)
#define BB 8
#define SEQ 2049
#define NT 2048
#define DD 1024
#define EE 8
#define SS 256
#define ESN 2048
#define HH 512

typedef __bf16 bf16x8 __attribute__((ext_vector_type(8)));
typedef float f32x4 __attribute__((ext_vector_type(4)));

__device__ __forceinline__ float gelu_f(float v) {
  return 0.5f * v * (1.0f + erff(v * 0.70710678118654752440f));
}
__device__ __forceinline__ float wave_sum(float v) {
#pragma unroll
  for (int off = 1; off < 64; off <<= 1) v += __shfl_xor(v, off);
  return v;
}
__device__ __forceinline__ unsigned short f2bf(float f) {
  unsigned int u = __float_as_uint(f);
  u = (u + 0x7fffu + ((u >> 16) & 1u)) >> 16;
  return (unsigned short)u;
}
__device__ __forceinline__ float bf2f(unsigned short h) {
  return __uint_as_float(((unsigned int)h) << 16);
}

// async 16B/lane global->LDS stage; lbase is wave-uniform, HW adds lane*16.
__device__ __forceinline__ void stage16(const unsigned short* g, unsigned short* lbase, int lane) {
#if __has_builtin(__builtin_amdgcn_global_load_lds)
  __builtin_amdgcn_global_load_lds((const __attribute__((address_space(1))) void*)g,
                                   (__attribute__((address_space(3))) void*)lbase, 16, 0, 0);
#else
  *(int4*)(lbase + lane * 8) = *(const int4*)g;
#endif
}

// XCD-aware bijective block remap (T1). All MFMA grids are divisible by 8.
__device__ __forceinline__ int3 xcd_map() {
  const int gx = gridDim.x, gy = gridDim.y;
  int bid = blockIdx.x + gx * (blockIdx.y + gy * blockIdx.z);
  const int q = (gx * gy * (int)gridDim.z) >> 3;
  bid = (bid & 7) * q + (bid >> 3);
  int3 r;
  r.x = bid % gx; bid /= gx;
  r.y = bid % gy;
  r.z = bid / gy;
  return r;
}

// ---- bf16 gemm_bt core: C[128x128]=A[m][k]*B[n][k]^T, K%64==0 ----
// BK=64 single-buffered, stage -> barrier -> compute -> barrier.
// LDS 32KB: A rows [128][64] at r*64, B at +8192 (shorts).
// T2 XOR-swizzle at 16B-group granularity (group' = group ^ (row&7)):
//   - LDS dest linear (global_load_lds requirement),
//   - staging SOURCE column pre-swizzled: lane group (l&7) ^ (l>>3),
//   - fragment reads XOR the same term: col ^ ((fr&7)<<3).
// Every access is exactly one 16B group, so the involution is exact; post-
// swizzle each quarter-group's 16 lanes cover all 32 banks 2-way (free).
__device__ __forceinline__ void gemm_core(const unsigned short* __restrict__ A,
                                          const unsigned short* __restrict__ B,
                                          int K, unsigned short* LDS, f32x4 acc[4][4]) {
  const int t = threadIdx.x;
  const int lane = t & 63, wave = t >> 6;
  const int srow = t >> 3;                               // row within 32-row stripe set
  const int scol = (((lane & 7) ^ (lane >> 3)) << 3);    // pre-swizzled source group
  const int fr = lane & 15, fk = (lane >> 4) * 8;
  const int fswz = (fr & 7) << 3;                        // read-side swizzle term
  const int wm = (wave >> 1) * 64, wn = (wave & 1) * 64;
  const unsigned short* ap = A + (size_t)srow * K + scol;
  const unsigned short* bp = B + (size_t)srow * K + scol;
  unsigned short* dA = LDS + wave * 512;
  unsigned short* dB = LDS + 8192 + wave * 512;
  for (int k0 = 0; k0 < K; k0 += 64) {
#pragma unroll
    for (int q = 0; q < 4; ++q) {
      stage16(ap + (size_t)(q * 32) * K + k0, dA + q * 2048, lane);
      stage16(bp + (size_t)(q * 32) * K + k0, dB + q * 2048, lane);
    }
    __syncthreads();  // drains vmcnt: staged tiles visible
#pragma unroll
    for (int kk = 0; kk < 2; ++kk) {
      bf16x8 bq[4];
#pragma unroll
      for (int j = 0; j < 4; ++j)
        bq[j] = *(const bf16x8*)(LDS + 8192 + (wn + j * 16 + fr) * 64 + ((kk * 32 + fk) ^ fswz));
#pragma unroll
      for (int ib = 0; ib < 2; ++ib) {
        bf16x8 afa = *(const bf16x8*)(LDS + (wm + (ib * 2) * 16 + fr) * 64 + ((kk * 32 + fk) ^ fswz));
        bf16x8 afb = *(const bf16x8*)(LDS + (wm + (ib * 2 + 1) * 16 + fr) * 64 + ((kk * 32 + fk) ^ fswz));
#pragma unroll
        for (int j = 0; j < 4; ++j)
          acc[ib * 2][j] = __builtin_amdgcn_mfma_f32_16x16x32_bf16(afa, bq[j], acc[ib * 2][j], 0, 0, 0);
#pragma unroll
        for (int j = 0; j < 4; ++j)
          acc[ib * 2 + 1][j] = __builtin_amdgcn_mfma_f32_16x16x32_bf16(afb, bq[j], acc[ib * 2 + 1][j], 0, 0, 0);
      }
    }
    __syncthreads();  // all reads done before next stage overwrites
  }
}

#define ACC_INIT()                                        \
  f32x4 acc[4][4];                                        \
  _Pragma("unroll") for (int i = 0; i < 4; ++i)           \
  _Pragma("unroll") for (int j = 0; j < 4; ++j)           \
  _Pragma("unroll") for (int r = 0; r < 4; ++r) acc[i][j][r] = 0.f;

#define GEMM_EPI_VARS()                                   \
  const int lane = threadIdx.x & 63, wave = threadIdx.x >> 6; \
  const int wm = (wave >> 1) * 64, wn = (wave & 1) * 64;  \
  const int fr16 = lane & 15, r4 = (lane >> 4) << 2;

// logits -> E16[n][c] direct (32B runs) + ET[c][n] via chunked LDS transpose.
__global__ __launch_bounds__(256, 4) void k_logits_mfma(const unsigned short* __restrict__ Xb,
    const unsigned short* __restrict__ MT, unsigned short* __restrict__ E16,
    unsigned short* __restrict__ ET) {
  __shared__ unsigned short LDS[16384];
  ACC_INIT();
  const int3 bi = xcd_map();
  const int b = bi.z, m0 = bi.x * 128, n0 = bi.y * 128;
  gemm_core(Xb + ((size_t)b * NT + m0) * DD, MT + (size_t)n0 * DD, DD, LDS, acc);
  GEMM_EPI_VARS();
  const int t = threadIdx.x;
  unsigned short* o = E16 + (size_t)b * NT * ESN;
#pragma unroll
  for (int i = 0; i < 4; ++i)
#pragma unroll
    for (int j = 0; j < 4; ++j) {
      const int gmb = m0 + wm + i * 16 + r4;
      const int gn = n0 + wn + j * 16 + fr16;
      o[(size_t)(gmb + 0) * ESN + gn] = f2bf(expf(acc[i][j][0]));
      o[(size_t)(gmb + 1) * ESN + gn] = f2bf(expf(acc[i][j][1]));
      o[(size_t)(gmb + 2) * ESN + gn] = f2bf(expf(acc[i][j][2]));
      o[(size_t)(gmb + 3) * ESN + gn] = f2bf(expf(acc[i][j][3]));
    }
  // two 64-column chunks: chunk h handled by waves with wn == h*64
#pragma unroll
  for (int h = 0; h < 2; ++h) {
    if ((wn >> 6) == h) {
#pragma unroll
      for (int i = 0; i < 4; ++i)
#pragma unroll
        for (int j = 0; j < 4; ++j) {
          ushort4 pk;
          pk.x = f2bf(expf(acc[i][j][0]));
          pk.y = f2bf(expf(acc[i][j][1]));
          pk.z = f2bf(expf(acc[i][j][2]));
          pk.w = f2bf(expf(acc[i][j][3]));
          // T[n-local][m-local], stride 132 (8B-aligned rows)
          *(ushort4*)(LDS + (j * 16 + fr16) * 132 + wm + i * 16 + r4) = pk;
        }
    }
    __syncthreads();
#pragma unroll
    for (int p = 0; p < 4; ++p) {
      const int nl = p * 16 + (t >> 4);
      const int ml = (t & 15) * 8;
      int4 v = *(const int4*)(LDS + nl * 132 + ml);
      *(int4*)(ET + ((size_t)b * ESN + n0 + h * 64 + nl) * NT + m0 + ml) = v;
    }
    __syncthreads();
  }
}

__global__ __launch_bounds__(256, 4) void k_slotin_mfma(const unsigned short* __restrict__ ET,
    const unsigned short* __restrict__ XT, const float* __restrict__ cinv,
    unsigned short* __restrict__ SI) {
  __shared__ unsigned short LDS[16384];
  ACC_INIT();
  const int3 bi = xcd_map();
  const int b = bi.z, m0 = bi.x * 128, n0 = bi.y * 128;
  gemm_core(ET + ((size_t)b * ESN + m0) * NT, XT + ((size_t)b * DD + n0) * NT, NT, LDS, acc);
  GEMM_EPI_VARS();
#pragma unroll
  for (int i = 0; i < 4; ++i)
#pragma unroll
    for (int j = 0; j < 4; ++j) {
      const int gmb = m0 + wm + i * 16 + r4;
      const int gn = n0 + wn + j * 16 + fr16;
#pragma unroll
      for (int r = 0; r < 4; ++r)
        SI[((size_t)b * ESN + gmb + r) * DD + gn] = f2bf(acc[i][j][r] * cinv[b * ESN + gmb + r]);
    }
}

__global__ __launch_bounds__(256, 4) void k_ffn1_mfma(const unsigned short* __restrict__ SI,
    const unsigned short* __restrict__ w1b, const float* __restrict__ b1,
    unsigned short* __restrict__ H1) {
  __shared__ unsigned short LDS[16384];
  ACC_INIT();
  const int3 bi = xcd_map();
  const int z = bi.z, b = z >> 3, e = z & 7;
  const int m0 = bi.x * 128, n0 = bi.y * 128;
  gemm_core(SI + ((size_t)b * ESN + e * SS + m0) * DD, w1b + ((size_t)e * HH + n0) * DD,
            DD, LDS, acc);
  GEMM_EPI_VARS();
#pragma unroll
  for (int i = 0; i < 4; ++i)
#pragma unroll
    for (int j = 0; j < 4; ++j) {
      const int gmb = m0 + wm + i * 16 + r4;
      const int gn = n0 + wn + j * 16 + fr16;
      const float bias = b1[e * HH + gn];
#pragma unroll
      for (int r = 0; r < 4; ++r)
        H1[((size_t)(b * EE + e) * SS + gmb + r) * HH + gn] = f2bf(gelu_f(acc[i][j][r] + bias));
    }
}

// ffn2 -> SOT[d][c] via chunked LDS transpose (coalesced 256B rows)
__global__ __launch_bounds__(256, 4) void k_ffn2_mfma(const unsigned short* __restrict__ H1,
    const unsigned short* __restrict__ w2b, const float* __restrict__ b2,
    unsigned short* __restrict__ SOT) {
  __shared__ unsigned short LDS[16384];
  ACC_INIT();
  const int3 bi = xcd_map();
  const int z = bi.z, b = z >> 3, e = z & 7;
  const int m0 = bi.x * 128, n0 = bi.y * 128;   // m: s within expert, n: d
  gemm_core(H1 + ((size_t)(b * EE + e) * SS + m0) * HH, w2b + ((size_t)e * DD + n0) * HH,
            HH, LDS, acc);
  GEMM_EPI_VARS();
  const int t = threadIdx.x;
#pragma unroll
  for (int h = 0; h < 2; ++h) {
    if ((wn >> 6) == h) {
#pragma unroll
      for (int i = 0; i < 4; ++i)
#pragma unroll
        for (int j = 0; j < 4; ++j) {
          const float bias = b2[e * DD + n0 + wn + j * 16 + fr16];
          ushort4 pk;
          pk.x = f2bf(acc[i][j][0] + bias);
          pk.y = f2bf(acc[i][j][1] + bias);
          pk.z = f2bf(acc[i][j][2] + bias);
          pk.w = f2bf(acc[i][j][3] + bias);
          *(ushort4*)(LDS + (j * 16 + fr16) * 132 + wm + i * 16 + r4) = pk;
        }
    }
    __syncthreads();
#pragma unroll
    for (int p = 0; p < 4; ++p) {
      const int dl = p * 16 + (t >> 4);
      const int ml = (t & 15) * 8;
      int4 v = *(const int4*)(LDS + dl * 132 + ml);
      *(int4*)(SOT + ((size_t)b * DD + n0 + h * 64 + dl) * ESN + e * SS + m0 + ml) = v;
    }
    __syncthreads();
  }
}

__global__ __launch_bounds__(256, 4) void k_img_mfma(const unsigned short* __restrict__ E16,
    const unsigned short* __restrict__ SOT, const float* __restrict__ rinv,
    float* __restrict__ out) {
  __shared__ unsigned short LDS[16384];
  ACC_INIT();
  const int3 bi = xcd_map();
  const int b = bi.z, m0 = bi.x * 128, n0 = bi.y * 128;
  gemm_core(E16 + ((size_t)b * NT + m0) * ESN, SOT + ((size_t)b * DD + n0) * ESN,
            ESN, LDS, acc);
  GEMM_EPI_VARS();
#pragma unroll
  for (int i = 0; i < 4; ++i)
#pragma unroll
    for (int j = 0; j < 4; ++j) {
      const int gmb = m0 + wm + i * 16 + r4;
      const int gn = n0 + wn + j * 16 + fr16;
#pragma unroll
      for (int r = 0; r < 4; ++r)
        out[((size_t)b * SEQ + 1 + gmb + r) * DD + gn] = acc[i][j][r] * rinv[b * NT + gmb + r];
    }
}

// -------- packing --------
__global__ __launch_bounds__(256) void k_xnf(const float* __restrict__ x, float* __restrict__ xnf) {
  const int wid = blockIdx.x * 4 + (threadIdx.x >> 6);
  const int lane = threadIdx.x & 63;
  const int b = wid >> 11;
  const float* row = x + ((size_t)b * SEQ + 1 + (wid & (NT - 1))) * DD;
  float s = 0.f;
#pragma unroll
  for (int k = 0; k < DD / 64; ++k) { const float v = row[lane + k * 64]; s = fmaf(v, v, s); }
  s = wave_sum(s);
  if (lane == 0) xnf[wid] = 1.0f / fmaxf(sqrtf(s), 1e-12f);
}

// mu column-norm, 2-stage
__global__ __launch_bounds__(256) void k_munf_part(const float* __restrict__ mu,
    float* __restrict__ pm) {
  const int c = blockIdx.x * 256 + threadIdx.x;
  const int d0 = blockIdx.y * (DD / 16);
  float s = 0.f;
  for (int d = d0; d < d0 + DD / 16; ++d) {
    const float v = mu[(size_t)d * ESN + c];
    s = fmaf(v, v, s);
  }
  pm[blockIdx.y * ESN + c] = s;
}

__global__ __launch_bounds__(256) void k_munf_red(const float* __restrict__ pm,
    const float* __restrict__ scale, float* __restrict__ munf) {
  const int c = blockIdx.x * 256 + threadIdx.x;
  float s = 0.f;
#pragma unroll
  for (int k = 0; k < 16; ++k) s += pm[k * ESN + c];
  munf[c] = scale[0] / fmaxf(sqrtf(s), 1e-12f);
}

__global__ __launch_bounds__(256) void k_pack_x(const float* __restrict__ x,
    const float* __restrict__ xnf, unsigned short* __restrict__ Xb,
    unsigned short* __restrict__ XT) {
  __shared__ unsigned short tile[64][72];
  const int b = blockIdx.z, n0 = blockIdx.x * 64, d0 = blockIdx.y * 64;
  const int t = threadIdx.x, tr = t >> 2, tc = (t & 3) * 16;
  const float* s = x + ((size_t)b * SEQ + 1 + n0 + tr) * DD + d0 + tc;
  const float xs = xnf[b * NT + n0 + tr];
  unsigned short tmp[16];
#pragma unroll
  for (int j = 0; j < 16; j += 4) {
    float4 v = *(const float4*)(s + j);
    tmp[j] = f2bf(v.x * xs); tmp[j + 1] = f2bf(v.y * xs);
    tmp[j + 2] = f2bf(v.z * xs); tmp[j + 3] = f2bf(v.w * xs);
  }
  *(int4*)&tile[tr][tc] = *(int4*)tmp;
  *(int4*)&tile[tr][tc + 8] = *(int4*)(tmp + 8);
  unsigned short* xb = Xb + ((size_t)b * NT + n0 + tr) * DD + d0 + tc;
  *(int4*)xb = *(int4*)tmp;
  *(int4*)(xb + 8) = *(int4*)(tmp + 8);
  __syncthreads();
  unsigned short* d = XT + ((size_t)b * DD + d0 + tr) * NT + n0 + tc;
#pragma unroll
  for (int j = 0; j < 16; ++j) tmp[j] = tile[tc + j][tr];
  *(int4*)d = *(int4*)tmp;
  *(int4*)(d + 8) = *(int4*)(tmp + 8);
}

__global__ __launch_bounds__(256) void k_pack_mu(const float* __restrict__ mu,
    const float* __restrict__ munf, unsigned short* __restrict__ MT) {
  __shared__ unsigned short tile[64][72];
  const int d0 = blockIdx.x * 64, c0 = blockIdx.y * 64;
  const int t = threadIdx.x, tr = t >> 2, tc = (t & 3) * 16;
  const float* s = mu + (size_t)(d0 + tr) * ESN + c0 + tc;
  unsigned short tmp[16];
#pragma unroll
  for (int j = 0; j < 16; j += 4) {
    float4 v = *(const float4*)(s + j);
    tmp[j] = f2bf(v.x * munf[c0 + tc + j]);
    tmp[j + 1] = f2bf(v.y * munf[c0 + tc + j + 1]);
    tmp[j + 2] = f2bf(v.z * munf[c0 + tc + j + 2]);
    tmp[j + 3] = f2bf(v.w * munf[c0 + tc + j + 3]);
  }
  *(int4*)&tile[tr][tc] = *(int4*)tmp;
  *(int4*)&tile[tr][tc + 8] = *(int4*)(tmp + 8);
  __syncthreads();
  unsigned short* d = MT + (size_t)(c0 + tr) * DD + d0 + tc;
#pragma unroll
  for (int j = 0; j < 16; ++j) tmp[j] = tile[tc + j][tr];
  *(int4*)d = *(int4*)tmp;
  *(int4*)(d + 8) = *(int4*)(tmp + 8);
}

__global__ __launch_bounds__(256) void k_packw(const float* __restrict__ w,
    unsigned short* __restrict__ o, int n4) {
  const int i = blockIdx.x * 256 + threadIdx.x;
  if (i < n4) {
    float4 v = ((const float4*)w)[i];
    ushort4 u;
    u.x = f2bf(v.x); u.y = f2bf(v.y); u.z = f2bf(v.z); u.w = f2bf(v.w);
    ((ushort4*)o)[i] = u;
  }
}

// -------- softmax stats --------
__global__ __launch_bounds__(256) void k_rowstats_e(const unsigned short* __restrict__ E,
    float* __restrict__ rinv, float* __restrict__ t_r2, float* __restrict__ t_dr) {
  const int wid = blockIdx.x * 4 + (threadIdx.x >> 6);  // b*NT + n
  const int lane = threadIdx.x & 63;
  const int n = wid & (NT - 1);
  const unsigned short* row = E + (size_t)wid * ESN;
  float s1 = 0.f, s2 = 0.f;
#pragma unroll
  for (int it = 0; it < 4; ++it) {
    int4 v = *(const int4*)(row + it * 512 + lane * 8);
    const unsigned short* u = (const unsigned short*)&v;
#pragma unroll
    for (int j = 0; j < 8; ++j) { const float e = bf2f(u[j]); s1 += e; s2 = fmaf(e, e, s2); }
  }
  s1 = wave_sum(s1); s2 = wave_sum(s2);
  if (lane == 0) {
    const float ri = 1.0f / s1;
    rinv[wid] = ri;
    const float r2 = 1.0f / (s2 * ri * ri + 1e-9f);
    t_r2[wid] = r2;
    t_dr[wid] = bf2f(row[n]) * ri * r2;
  }
}

__global__ __launch_bounds__(256) void k_colstats(const unsigned short* __restrict__ ET,
    float* __restrict__ cinv, float* __restrict__ t_rs2, float* __restrict__ t_sd) {
  const int wid = blockIdx.x * 4 + (threadIdx.x >> 6);  // b*ESN + c
  const int lane = threadIdx.x & 63;
  const unsigned short* row = ET + (size_t)wid * NT;
  float s1 = 0.f, s2 = 0.f;
#pragma unroll
  for (int it = 0; it < 4; ++it) {
    int4 v = *(const int4*)(row + it * 512 + lane * 8);
    const unsigned short* u = (const unsigned short*)&v;
#pragma unroll
    for (int j = 0; j < 8; ++j) { const float e = bf2f(u[j]); s1 += e; s2 = fmaf(e, e, s2); }
  }
  s1 = wave_sum(s1); s2 = wave_sum(s2);
  if (lane == 0) {
    const float ci = 1.0f / s1;
    cinv[wid] = ci;
    const float rs2 = 1.0f / (s2 * ci * ci + 1e-9f);
    t_rs2[wid] = rs2;
    const int c = wid & (ESN - 1);
    t_sd[wid] = ((c % 257) == 0) ? rs2 : 0.f;
  }
}

// -------- cls path --------
__global__ __launch_bounds__(256) void k_clsA(const float* __restrict__ x,
    const float* __restrict__ w1, const float* __restrict__ b1, float* __restrict__ clsh) {
  const int wid = blockIdx.x * 4 + (threadIdx.x >> 6);
  const int lane = threadIdx.x & 63;
  const int b = wid >> 9, h = wid & (HH - 1);
  const float* xr = x + (size_t)b * SEQ * DD;
  const float* wr = w1 + (size_t)h * DD;
  float s = 0.f;
#pragma unroll
  for (int k = 0; k < DD / 64; ++k) s = fmaf(xr[lane + k * 64], wr[lane + k * 64], s);
  s = wave_sum(s);
  if (lane == 0) clsh[wid] = gelu_f(s + b1[h]);
}

__global__ __launch_bounds__(256) void k_clsB(const float* __restrict__ clsh,
    const float* __restrict__ w2, const float* __restrict__ b2, float* __restrict__ out) {
  const int wid = blockIdx.x * 4 + (threadIdx.x >> 6);
  const int lane = threadIdx.x & 63;
  const int b = wid >> 10, d = wid & (DD - 1);
  const float* hr = clsh + (size_t)b * HH;
  const float* wr = w2 + (size_t)d * HH;
  float s = 0.f;
#pragma unroll
  for (int k = 0; k < HH / 64; ++k) s = fmaf(hr[lane + k * 64], wr[lane + k * 64], s);
  s = wave_sum(s);
  if (lane == 0) out[(size_t)b * SEQ * DD + d] = s + b2[d];
}

__global__ __launch_bounds__(256) void k_metrics(const float* __restrict__ t_r2,
    const float* __restrict__ t_dr, const float* __restrict__ t_rs2,
    const float* __restrict__ t_sd, float* __restrict__ out) {
  __shared__ float sm[256];
  const int tid = threadIdx.x;
  float a = 0.f, b = 0.f, c = 0.f, d = 0.f;
  for (int i = tid; i < BB * NT; i += 256) { a += t_r2[i]; b += t_dr[i]; }
  for (int i = tid; i < BB * ESN; i += 256) { c += t_rs2[i]; d += t_sd[i]; }
  float vals[4] = {a, b, c, d};
  float res[4];
#pragma unroll
  for (int v = 0; v < 4; ++v) {
    sm[tid] = vals[v];
    __syncthreads();
    for (int s = 128; s > 0; s >>= 1) {
      if (tid < s) sm[tid] += sm[tid + s];
      __syncthreads();
    }
    res[v] = sm[0];
    __syncthreads();
  }
  if (tid == 0) {
    out[(size_t)BB * SEQ * DD] = (res[0] - res[1]) / 33538048.0f;
    out[(size_t)BB * SEQ * DD + 1] = (res[2] - res[3]) / 33538048.0f;
  }
}

extern "C" void kernel_launch(void* const* d_in, const int* in_sizes, int n_in,
                              void* d_out, int out_size, void* d_ws, size_t ws_size,
                              hipStream_t stream) {
  const float* x      = (const float*)d_in[0];
  const float* mu     = (const float*)d_in[1];
  const float* scale  = (const float*)d_in[2];
  const float* cls_w1 = (const float*)d_in[3];
  const float* cls_b1 = (const float*)d_in[4];
  const float* cls_w2 = (const float*)d_in[5];
  const float* cls_b2 = (const float*)d_in[6];
  const float* w1     = (const float*)d_in[7];
  const float* b1     = (const float*)d_in[8];
  const float* w2     = (const float*)d_in[9];
  const float* b2     = (const float*)d_in[10];
  float* out = (float*)d_out;

  // workspace plan (bytes), aliasing by lifetime:
  char* W = (char*)d_ws;
  unsigned short* XT  = (unsigned short*)(W);              // 32MB; H1 aliases after slotin
  unsigned short* Xb  = (unsigned short*)(W + 33554432);   // 32MB; SOT aliases after logits
  unsigned short* MT  = (unsigned short*)(W + 67108864);   //  4MB
  unsigned short* E16 = (unsigned short*)(W + 71303168);   // 64MB (written by logits; munf partials alias before that)
  unsigned short* ET  = (unsigned short*)(W + 138412032);  // 64MB; w1b/w2b alias after slotin
  unsigned short* SI  = (unsigned short*)(W + 205520896);  // 32MB
  unsigned short* H1  = (unsigned short*)(W);              // 16MB (alias XT)
  unsigned short* SOT = (unsigned short*)(W + 33554432);   // 32MB (alias Xb)
  unsigned short* w1b = (unsigned short*)(W + 138412032);  //  8MB (alias ET)
  unsigned short* w2b = (unsigned short*)(W + 146800640);  //  8MB (alias ET)
  float* pmunf = (float*)(W + 71303168);                   // 128KB (alias E16, dead before logits)
  float* F = (float*)(W + 239075328);
  float* xnf   = F;
  float* munf  = F + 16384;
  float* rinv  = F + 18432;
  float* t_r2  = F + 34816;
  float* t_dr  = F + 51200;
  float* cinv  = F + 67584;
  float* t_rs2 = F + 83968;
  float* t_sd  = F + 100352;
  float* clsh  = F + 116736;

  k_xnf<<<dim3(BB * NT / 4), 256, 0, stream>>>(x, xnf);
  k_munf_part<<<dim3(ESN / 256, 16), 256, 0, stream>>>(mu, pmunf);
  k_munf_red<<<dim3(ESN / 256), 256, 0, stream>>>(pmunf, scale, munf);
  k_pack_x<<<dim3(NT / 64, DD / 64, BB), 256, 0, stream>>>(x, xnf, Xb, XT);
  k_pack_mu<<<dim3(DD / 64, ESN / 64), 256, 0, stream>>>(mu, munf, MT);
  k_logits_mfma<<<dim3(NT / 128, ESN / 128, BB), 256, 0, stream>>>(Xb, MT, E16, ET);
  k_rowstats_e<<<dim3(BB * NT / 4), 256, 0, stream>>>(E16, rinv, t_r2, t_dr);
  k_colstats<<<dim3(BB * ESN / 4), 256, 0, stream>>>(ET, cinv, t_rs2, t_sd);
  k_slotin_mfma<<<dim3(ESN / 128, DD / 128, BB), 256, 0, stream>>>(ET, XT, cinv, SI);
  k_packw<<<dim3(EE * HH * DD / 4 / 256), 256, 0, stream>>>(w1, w1b, EE * HH * DD / 4);
  k_packw<<<dim3(EE * DD * HH / 4 / 256), 256, 0, stream>>>(w2, w2b, EE * DD * HH / 4);
  k_ffn1_mfma<<<dim3(SS / 128, HH / 128, BB * EE), 256, 0, stream>>>(SI, w1b, b1, H1);
  k_ffn2_mfma<<<dim3(SS / 128, DD / 128, BB * EE), 256, 0, stream>>>(H1, w2b, b2, SOT);
  k_img_mfma<<<dim3(NT / 128, DD / 128, BB), 256, 0, stream>>>(E16, SOT, rinv, out);
  k_clsA<<<dim3(BB * HH / 4), 256, 0, stream>>>(x, cls_w1, cls_b1, clsh);
  k_clsB<<<dim3(BB * DD / 4), 256, 0, stream>>>(clsh, cls_w2, cls_b2, out);
  k_metrics<<<1, 256, 0, stream>>>(t_r2, t_dr, t_rs2, t_sd, out);
}